// Round 5
// baseline (3001.659 us; speedup 1.0000x reference)
//
#include <hip/hip_runtime.h>

#define D 128
typedef unsigned long long ull;

// ---------------- degree histogram ----------------
__global__ void k_zero_int(int* p, int n) {
  int i = blockIdx.x * blockDim.x + threadIdx.x;
  if (i < n) p[i] = 0;
}

__global__ void k_deg_count(const int* __restrict__ ei, int* __restrict__ deg, int E) {
  int e = blockIdx.x * blockDim.x + threadIdx.x;
  if (e < E) atomicAdd(&deg[ei[E + e]], 1);  // dst row
}

// ---------------- prefix sum (CHUNK = 2048 = 256 threads x 8) ----------------
__global__ void k_scan_part(const int* __restrict__ deg, int* __restrict__ part, int n) {
  __shared__ int sd[256];
  int base = blockIdx.x * 2048 + threadIdx.x * 8;
  int s = 0;
#pragma unroll
  for (int k = 0; k < 8; k++) {
    int idx = base + k;
    if (idx < n) s += deg[idx];
  }
  sd[threadIdx.x] = s;
  __syncthreads();
  for (int off = 128; off > 0; off >>= 1) {
    if (threadIdx.x < off) sd[threadIdx.x] += sd[threadIdx.x + off];
    __syncthreads();
  }
  if (threadIdx.x == 0) part[blockIdx.x] = sd[0];
}

__global__ void k_scan_offsets(int* __restrict__ part, int nparts,
                               int* __restrict__ rowptr, int n) {
  __shared__ int sd[256];
  int v = (threadIdx.x < nparts) ? part[threadIdx.x] : 0;
  sd[threadIdx.x] = v;
  __syncthreads();
  for (int off = 1; off < 256; off <<= 1) {
    int t = (threadIdx.x >= off) ? sd[threadIdx.x - off] : 0;
    __syncthreads();
    sd[threadIdx.x] += t;
    __syncthreads();
  }
  if (threadIdx.x < nparts) part[threadIdx.x] = sd[threadIdx.x] - v;  // exclusive
  if (threadIdx.x == 0) rowptr[n] = sd[255];                          // total = E
}

__global__ void k_scan_final(const int* __restrict__ deg, const int* __restrict__ part,
                             int* __restrict__ rowptr, int n) {
  __shared__ int sd[256];
  int base = blockIdx.x * 2048 + threadIdx.x * 8;
  int loc[8];
  int s = 0;
#pragma unroll
  for (int k = 0; k < 8; k++) {
    int idx = base + k;
    loc[k] = (idx < n) ? deg[idx] : 0;
    s += loc[k];
  }
  sd[threadIdx.x] = s;
  __syncthreads();
  for (int off = 1; off < 256; off <<= 1) {
    int t = (threadIdx.x >= off) ? sd[threadIdx.x - off] : 0;
    __syncthreads();
    sd[threadIdx.x] += t;
    __syncthreads();
  }
  int run = part[blockIdx.x] + sd[threadIdx.x] - s;  // exclusive offset
#pragma unroll
  for (int k = 0; k < 8; k++) {
    int idx = base + k;
    if (idx < n) {
      rowptr[idx] = run;
      run += loc[k];
    }
  }
}

// dinv = rsqrt(in_deg + 1 self-loop); also init cursor = rowptr
__global__ void k_dinv_cursor(const int* __restrict__ rowptr, float* __restrict__ dinv,
                              int* __restrict__ cursor, int n) {
  int i = blockIdx.x * blockDim.x + threadIdx.x;
  if (i < n) {
    int r0 = rowptr[i], r1 = rowptr[i + 1];
    dinv[i] = rsqrtf((float)(r1 - r0) + 1.0f);
    cursor[i] = r0;
  }
}

// bucketed fill: only edges whose dst is in [lo,hi) are placed this pass.
// packed entry = src | (float_bits(norm) << 32)
__global__ void k_csr_fill_b(const int* __restrict__ ei, const float* __restrict__ dinv,
                             int* __restrict__ cursor, ull* __restrict__ packed,
                             int E, int lo, int hi) {
  int e = blockIdx.x * blockDim.x + threadIdx.x;
  if (e >= E) return;
  int d = __builtin_nontemporal_load(&ei[E + e]);
  if (d < lo || d >= hi) return;
  int s = __builtin_nontemporal_load(&ei[e]);
  float nrm = dinv[s] * dinv[d];
  int pos = atomicAdd(&cursor[d], 1);
  packed[pos] = (ull)(unsigned)s | ((ull)__float_as_uint(nrm) << 32);
}

// ---------------- GEMM: C_sliced[16][n][8] = A[n,128] @ W[128,128] ----------------
// A staged transposed in LDS (66 KB -> 2 blocks/CU); W read from global (L1/L2-resident).
// SLICED_IN: A is in [16][n][8] sliced layout; else row-major [n][128].
template <int SLICED_IN>
__launch_bounds__(256, 2)
__global__ void k_gemm(const float* __restrict__ A, const float* __restrict__ W,
                       float* __restrict__ Csl, int n) {
  __shared__ float As[D * 129];     // [k][row] transposed, pad 129
  const int tid = threadIdx.x;
  const int row0 = blockIdx.x * 128;
  const size_t SN = (size_t)n * 8;  // slice stride (floats)

  for (int i = tid; i < 128 * 32; i += 256) {
    int r = i >> 5;
    int k4 = (i & 31) << 2;
    int gr = row0 + r;
    float4 v = make_float4(0.f, 0.f, 0.f, 0.f);
    if (gr < n) {
      if (SLICED_IN)
        v = *(const float4*)&A[(size_t)(k4 >> 3) * SN + (size_t)gr * 8 + (k4 & 7)];
      else
        v = ((const float4*)A)[(size_t)gr * 32 + (i & 31)];
    }
    As[(k4 + 0) * 129 + r] = v.x;
    As[(k4 + 1) * 129 + r] = v.y;
    As[(k4 + 2) * 129 + r] = v.z;
    As[(k4 + 3) * 129 + r] = v.w;
  }
  __syncthreads();

  const int tx = tid & 15;
  const int ty = tid >> 4;
  const int c0 = tx * 4;
  const int r0 = ty * 4;

  float acc[8][8];
#pragma unroll
  for (int i = 0; i < 8; i++)
#pragma unroll
    for (int j = 0; j < 8; j++) acc[i][j] = 0.f;

#pragma unroll 4
  for (int k = 0; k < D; k++) {
    float4 a0 = *(const float4*)&As[k * 129 + r0];
    float4 a1 = *(const float4*)&As[k * 129 + r0 + 64];
    float4 w0 = *(const float4*)&W[k * D + c0];        // global, L1/L2 hit
    float4 w1 = *(const float4*)&W[k * D + c0 + 64];
    float av[8] = {a0.x, a0.y, a0.z, a0.w, a1.x, a1.y, a1.z, a1.w};
    float wv[8] = {w0.x, w0.y, w0.z, w0.w, w1.x, w1.y, w1.z, w1.w};
#pragma unroll
    for (int i = 0; i < 8; i++)
#pragma unroll
      for (int j = 0; j < 8; j++) acc[i][j] = fmaf(av[i], wv[j], acc[i][j]);
  }

  const int sl0 = c0 >> 3;         // slice of cols c0..c0+3
  const int off = c0 & 7;          // 0 or 4
#pragma unroll
  for (int i = 0; i < 8; i++) {
    int gr = row0 + r0 + (i & 3) + (i >> 2) * 64;
    if (gr < n) {
      *(float4*)&Csl[(size_t)sl0 * SN + (size_t)gr * 8 + off] =
          make_float4(acc[i][0], acc[i][1], acc[i][2], acc[i][3]);
      *(float4*)&Csl[(size_t)(sl0 + 8) * SN + (size_t)gr * 8 + off] =
          make_float4(acc[i][4], acc[i][5], acc[i][6], acc[i][7]);
    }
  }
}

// ---------------- sliced pull aggregation ----------------
// grid = 8 * CHUNKS blocks; slice = (blockIdx&7) | (phase<<3) -> one slice per XCD
// (blockIdx%8 -> XCD round-robin): each XCD's 3.2MB slice stays L2-resident.
// 8-lane group per node; lane owns 1 of the slice's 8 columns.
// MODE 0: relu -> sliced out; MODE 1: relu(+res) -> sliced out; MODE 2: raw -> ROW-MAJOR out.
template <int MODE>
__launch_bounds__(256)
__global__ void k_agg_sl(const int* __restrict__ rowptr, const ull* __restrict__ packed,
                         const float* __restrict__ dinv, const float* __restrict__ tsl,
                         const float* __restrict__ bias, const float* __restrict__ ressl,
                         float* __restrict__ outp, int n, int phase) {
  const int slice = (blockIdx.x & 7) | (phase << 3);
  const int chunk = blockIdx.x >> 3;
  const int nchunks = gridDim.x >> 3;
  const int g = threadIdx.x >> 3;    // 32 groups / block
  const int l8 = threadIdx.x & 7;
  const size_t SN = (size_t)n * 8;
  const float* ts = tsl + (size_t)slice * SN;
  const float bb = bias[slice * 8 + l8];

  const int npb = (n + nchunks * 32 - 1) / (nchunks * 32);
  const int base = chunk * npb * 32;

  for (int it = 0; it < npb; ++it) {
    int node = base + it * 32 + g;
    if (node >= n) break;
    int beg = rowptr[node];
    int end = rowptr[node + 1];
    float dd = dinv[node];
    float acc = fmaf(ts[(size_t)node * 8 + l8], dd * dd, bb);

    int j = beg;
    for (; j + 4 <= end; j += 4) {
      ull q0 = __builtin_nontemporal_load(&packed[j + 0]);
      ull q1 = __builtin_nontemporal_load(&packed[j + 1]);
      ull q2 = __builtin_nontemporal_load(&packed[j + 2]);
      ull q3 = __builtin_nontemporal_load(&packed[j + 3]);
      float v0 = ts[(size_t)(unsigned)q0 * 8 + l8];
      float v1 = ts[(size_t)(unsigned)q1 * 8 + l8];
      float v2 = ts[(size_t)(unsigned)q2 * 8 + l8];
      float v3 = ts[(size_t)(unsigned)q3 * 8 + l8];
      acc = fmaf(v0, __uint_as_float((unsigned)(q0 >> 32)), acc);
      acc = fmaf(v1, __uint_as_float((unsigned)(q1 >> 32)), acc);
      acc = fmaf(v2, __uint_as_float((unsigned)(q2 >> 32)), acc);
      acc = fmaf(v3, __uint_as_float((unsigned)(q3 >> 32)), acc);
    }
    for (; j < end; ++j) {
      ull q = __builtin_nontemporal_load(&packed[j]);
      float v = ts[(size_t)(unsigned)q * 8 + l8];
      acc = fmaf(v, __uint_as_float((unsigned)(q >> 32)), acc);
    }

    if (MODE == 1) acc += ressl[(size_t)slice * SN + (size_t)node * 8 + l8];
    if (MODE == 0 || MODE == 1) acc = fmaxf(acc, 0.f);

    if (MODE == 2)
      __builtin_nontemporal_store(acc, &outp[(size_t)node * D + slice * 8 + l8]);
    else
      __builtin_nontemporal_store(acc, &outp[(size_t)slice * SN + (size_t)node * 8 + l8]);
  }
}

extern "C" void kernel_launch(void* const* d_in, const int* in_sizes, int n_in,
                              void* d_out, int out_size, void* d_ws, size_t ws_size,
                              hipStream_t stream) {
  const float* x  = (const float*)d_in[0];
  const int*   ei = (const int*)d_in[1];
  const float* W0 = (const float*)d_in[2];
  const float* b0 = (const float*)d_in[3];
  const float* W1 = (const float*)d_in[4];
  const float* b1 = (const float*)d_in[5];
  const float* W2 = (const float*)d_in[6];
  const float* b2 = (const float*)d_in[7];
  float* out = (float*)d_out;

  const int N = in_sizes[0] / D;   // 100000
  const int E = in_sizes[1] / 2;   // 3200000

  char* wsb = (char*)d_ws;
  auto alloc = [&](size_t elems) {
    char* p = wsb;
    wsb += ((elems * 4 + 255) & ~(size_t)255);
    return p;
  };
  int*   rowptr = (int*)alloc(N + 1);
  int*   cursor = (int*)alloc(N);      // also deg histogram
  int*   part   = (int*)alloc(256);
  float* dinv   = (float*)alloc(N);
  ull*   packed = (ull*)alloc(2 * (size_t)E);
  float* t      = (float*)alloc((size_t)N * D);   // sliced [16][N][8]
  float* g1     = (float*)alloc((size_t)N * D);   // sliced
  float* h2     = out;                            // d_out doubles as sliced h2 scratch

  dim3 b256(256);
  int gN   = (N + 255) / 256;
  int gE   = (E + 255) / 256;
  int gGem = (N + 127) / 128;
  int gAgg = 8 * 256;               // 8 slices x 256 chunks
  int nparts = (N + 2047) / 2048;

  // ---- CSR build ----
  int* deg = cursor;
  k_zero_int<<<gN, b256, 0, stream>>>(deg, N);
  k_deg_count<<<gE, b256, 0, stream>>>(ei, deg, E);
  k_scan_part<<<nparts, b256, 0, stream>>>(deg, part, N);
  k_scan_offsets<<<1, b256, 0, stream>>>(part, nparts, rowptr, N);
  k_scan_final<<<nparts, b256, 0, stream>>>(deg, part, rowptr, N);
  k_dinv_cursor<<<gN, b256, 0, stream>>>(rowptr, dinv, cursor, N);
  const int NB = 8;
  int bsz = (N + NB - 1) / NB;
  for (int b = 0; b < NB; b++) {
    int lo = b * bsz;
    int hi = lo + bsz;
    if (hi > N) hi = N;
    k_csr_fill_b<<<gE, b256, 0, stream>>>(ei, dinv, cursor, packed, E, lo, hi);
  }

  // ---- layer 0: g1 = relu(Agg(x@W0) + b0) ----
  k_gemm<0><<<gGem, b256, 0, stream>>>(x, W0, t, N);
  for (int ph = 0; ph < 2; ph++)
    k_agg_sl<0><<<gAgg, b256, 0, stream>>>(rowptr, packed, dinv, t, b0, nullptr, g1, N, ph);

  // ---- layer 1: h2 = relu(Agg(g1@W1) + b1 + g1) ----
  k_gemm<1><<<gGem, b256, 0, stream>>>(g1, W1, t, N);
  for (int ph = 0; ph < 2; ph++)
    k_agg_sl<1><<<gAgg, b256, 0, stream>>>(rowptr, packed, dinv, t, b1, g1, h2, N, ph);

  // ---- layer 2: out = Agg(h2@W2) + b2  (row-major into d_out) ----
  k_gemm<1><<<gGem, b256, 0, stream>>>(h2, W2, t, N);
  for (int ph = 0; ph < 2; ph++)
    k_agg_sl<2><<<gAgg, b256, 0, stream>>>(rowptr, packed, dinv, t, b2, nullptr, out, N, ph);
}

// Round 6
// 1246.092 us; speedup vs baseline: 2.4089x; 2.4089x over previous
//
#include <hip/hip_runtime.h>

#define D 128
typedef unsigned long long ull;

// ---------------- degree histogram ----------------
__global__ void k_zero_int(int* p, int n) {
  int i = blockIdx.x * blockDim.x + threadIdx.x;
  if (i < n) p[i] = 0;
}

__global__ void k_deg_count(const int* __restrict__ ei, int* __restrict__ deg, int E) {
  int e = blockIdx.x * blockDim.x + threadIdx.x;
  if (e < E) atomicAdd(&deg[ei[E + e]], 1);  // dst row
}

// ---------------- prefix sum (CHUNK = 2048 = 256 threads x 8) ----------------
__global__ void k_scan_part(const int* __restrict__ deg, int* __restrict__ part, int n) {
  __shared__ int sd[256];
  int base = blockIdx.x * 2048 + threadIdx.x * 8;
  int s = 0;
#pragma unroll
  for (int k = 0; k < 8; k++) {
    int idx = base + k;
    if (idx < n) s += deg[idx];
  }
  sd[threadIdx.x] = s;
  __syncthreads();
  for (int off = 128; off > 0; off >>= 1) {
    if (threadIdx.x < off) sd[threadIdx.x] += sd[threadIdx.x + off];
    __syncthreads();
  }
  if (threadIdx.x == 0) part[blockIdx.x] = sd[0];
}

__global__ void k_scan_offsets(int* __restrict__ part, int nparts,
                               int* __restrict__ rowptr, int n) {
  __shared__ int sd[256];
  int v = (threadIdx.x < nparts) ? part[threadIdx.x] : 0;
  sd[threadIdx.x] = v;
  __syncthreads();
  for (int off = 1; off < 256; off <<= 1) {
    int t = (threadIdx.x >= off) ? sd[threadIdx.x - off] : 0;
    __syncthreads();
    sd[threadIdx.x] += t;
    __syncthreads();
  }
  if (threadIdx.x < nparts) part[threadIdx.x] = sd[threadIdx.x] - v;  // exclusive
  if (threadIdx.x == 0) rowptr[n] = sd[255];                          // total = E
}

__global__ void k_scan_final(const int* __restrict__ deg, const int* __restrict__ part,
                             int* __restrict__ rowptr, int n) {
  __shared__ int sd[256];
  int base = blockIdx.x * 2048 + threadIdx.x * 8;
  int loc[8];
  int s = 0;
#pragma unroll
  for (int k = 0; k < 8; k++) {
    int idx = base + k;
    loc[k] = (idx < n) ? deg[idx] : 0;
    s += loc[k];
  }
  sd[threadIdx.x] = s;
  __syncthreads();
  for (int off = 1; off < 256; off <<= 1) {
    int t = (threadIdx.x >= off) ? sd[threadIdx.x - off] : 0;
    __syncthreads();
    sd[threadIdx.x] += t;
    __syncthreads();
  }
  int run = part[blockIdx.x] + sd[threadIdx.x] - s;  // exclusive offset
#pragma unroll
  for (int k = 0; k < 8; k++) {
    int idx = base + k;
    if (idx < n) {
      rowptr[idx] = run;
      run += loc[k];
    }
  }
}

// dinv = rsqrt(in_deg + 1 self-loop); also init cursor = rowptr
__global__ void k_dinv_cursor(const int* __restrict__ rowptr, float* __restrict__ dinv,
                              int* __restrict__ cursor, int n) {
  int i = blockIdx.x * blockDim.x + threadIdx.x;
  if (i < n) {
    int r0 = rowptr[i], r1 = rowptr[i + 1];
    dinv[i] = rsqrtf((float)(r1 - r0) + 1.0f);
    cursor[i] = r0;
  }
}

// bucketed fill: only edges whose dst is in [lo,hi) are placed this pass.
// entry = src (int32). per-pass write region = E/4*4B = 3.2MB -> L2-resident.
__global__ void k_csr_fill_b(const int* __restrict__ ei, int* __restrict__ cursor,
                             int* __restrict__ csr, int E, int lo, int hi) {
  int e = blockIdx.x * blockDim.x + threadIdx.x;
  if (e >= E) return;
  int d = __builtin_nontemporal_load(&ei[E + e]);
  if (d < lo || d >= hi) return;
  int s = __builtin_nontemporal_load(&ei[e]);
  int pos = atomicAdd(&cursor[d], 1);
  csr[pos] = s;
}

// ---------------- GEMM: C[n,128] = (A[n,128] @ W[128,128]) * dinv[row] ----------------
// A staged transposed in LDS (66 KB -> 2 blocks/CU); W read via L1/L2.
__launch_bounds__(256, 2)
__global__ void k_gemm(const float* __restrict__ A, const float* __restrict__ W,
                       const float* __restrict__ dinv, float* __restrict__ C, int n) {
  __shared__ float As[D * 129];     // [k][row] transposed, pad 129
  const int tid = threadIdx.x;
  const int row0 = blockIdx.x * 128;

  for (int i = tid; i < 128 * 32; i += 256) {
    int r = i >> 5;
    int k4 = (i & 31) << 2;
    int gr = row0 + r;
    float4 v = make_float4(0.f, 0.f, 0.f, 0.f);
    if (gr < n) v = ((const float4*)A)[(size_t)gr * 32 + (i & 31)];
    As[(k4 + 0) * 129 + r] = v.x;
    As[(k4 + 1) * 129 + r] = v.y;
    As[(k4 + 2) * 129 + r] = v.z;
    As[(k4 + 3) * 129 + r] = v.w;
  }
  __syncthreads();

  const int tx = tid & 15;
  const int ty = tid >> 4;
  const int c0 = tx * 4;
  const int r0 = ty * 4;

  float acc[8][8];
#pragma unroll
  for (int i = 0; i < 8; i++)
#pragma unroll
    for (int j = 0; j < 8; j++) acc[i][j] = 0.f;

#pragma unroll 4
  for (int k = 0; k < D; k++) {
    float4 a0 = *(const float4*)&As[k * 129 + r0];
    float4 a1 = *(const float4*)&As[k * 129 + r0 + 64];
    float4 w0 = *(const float4*)&W[k * D + c0];        // L1/L2 hit
    float4 w1 = *(const float4*)&W[k * D + c0 + 64];
    float av[8] = {a0.x, a0.y, a0.z, a0.w, a1.x, a1.y, a1.z, a1.w};
    float wv[8] = {w0.x, w0.y, w0.z, w0.w, w1.x, w1.y, w1.z, w1.w};
#pragma unroll
    for (int i = 0; i < 8; i++)
#pragma unroll
      for (int j = 0; j < 8; j++) acc[i][j] = fmaf(av[i], wv[j], acc[i][j]);
  }

#pragma unroll
  for (int i = 0; i < 8; i++) {
    int gr = row0 + r0 + (i & 3) + (i >> 2) * 64;
    if (gr < n) {
      float sc = dinv[gr];   // fold src-side norm into rows
      *(float4*)&C[(size_t)gr * D + c0] =
          make_float4(acc[i][0] * sc, acc[i][1] * sc, acc[i][2] * sc, acc[i][3] * sc);
      *(float4*)&C[(size_t)gr * D + c0 + 64] =
          make_float4(acc[i][4] * sc, acc[i][5] * sc, acc[i][6] * sc, acc[i][7] * sc);
    }
  }
}

// ---------------- pull-style aggregation ----------------
// t is pre-scaled by dinv[row]:  out[d] = dinv[d]*(t'[d] + sum t'[src]) + b  [+res] [relu]
// 2 nodes per wave: lanes 0-31 node A, lanes 32-63 node B; lane holds float4.
// MODE 0: relu; MODE 1: relu(+res); MODE 2: raw
template <int MODE>
__launch_bounds__(256)
__global__ void k_aggregate(const int* __restrict__ rowptr, const int* __restrict__ csr,
                            const float* __restrict__ dinv, const float* __restrict__ t,
                            const float* __restrict__ b, const float* __restrict__ res,
                            float* __restrict__ out, int n) {
  const int wid = threadIdx.x >> 6;
  const int half = (threadIdx.x >> 5) & 1;
  const int l32 = threadIdx.x & 31;
  int node = blockIdx.x * 8 + wid * 2 + half;
  if (node >= n) return;

  int beg = rowptr[node];
  int end = rowptr[node + 1];
  float dd = dinv[node];

  const float4* t4 = (const float4*)t;
  float4 acc = t4[(size_t)node * 32 + l32];   // self term (t' already src-scaled)

  int j = beg;
  for (; j + 4 <= end; j += 4) {
    int s0 = __builtin_nontemporal_load(&csr[j + 0]);
    int s1 = __builtin_nontemporal_load(&csr[j + 1]);
    int s2 = __builtin_nontemporal_load(&csr[j + 2]);
    int s3 = __builtin_nontemporal_load(&csr[j + 3]);
    float4 v0 = t4[(size_t)(unsigned)s0 * 32 + l32];
    float4 v1 = t4[(size_t)(unsigned)s1 * 32 + l32];
    float4 v2 = t4[(size_t)(unsigned)s2 * 32 + l32];
    float4 v3 = t4[(size_t)(unsigned)s3 * 32 + l32];
    acc.x += v0.x + v1.x + v2.x + v3.x;
    acc.y += v0.y + v1.y + v2.y + v3.y;
    acc.z += v0.z + v1.z + v2.z + v3.z;
    acc.w += v0.w + v1.w + v2.w + v3.w;
  }
  for (; j < end; ++j) {
    int s = __builtin_nontemporal_load(&csr[j]);
    float4 v = t4[(size_t)(unsigned)s * 32 + l32];
    acc.x += v.x; acc.y += v.y; acc.z += v.z; acc.w += v.w;
  }

  float4 bb = ((const float4*)b)[l32];
  acc.x = fmaf(acc.x, dd, bb.x);
  acc.y = fmaf(acc.y, dd, bb.y);
  acc.z = fmaf(acc.z, dd, bb.z);
  acc.w = fmaf(acc.w, dd, bb.w);

  if (MODE == 1) {
    float4 rr = ((const float4*)res)[(size_t)node * 32 + l32];
    acc.x += rr.x; acc.y += rr.y; acc.z += rr.z; acc.w += rr.w;
  }
  if (MODE == 0 || MODE == 1) {
    acc.x = fmaxf(acc.x, 0.f);
    acc.y = fmaxf(acc.y, 0.f);
    acc.z = fmaxf(acc.z, 0.f);
    acc.w = fmaxf(acc.w, 0.f);
  }
  ((float4*)out)[(size_t)node * 32 + l32] = acc;
}

extern "C" void kernel_launch(void* const* d_in, const int* in_sizes, int n_in,
                              void* d_out, int out_size, void* d_ws, size_t ws_size,
                              hipStream_t stream) {
  const float* x  = (const float*)d_in[0];
  const int*   ei = (const int*)d_in[1];
  const float* W0 = (const float*)d_in[2];
  const float* b0 = (const float*)d_in[3];
  const float* W1 = (const float*)d_in[4];
  const float* b1 = (const float*)d_in[5];
  const float* W2 = (const float*)d_in[6];
  const float* b2 = (const float*)d_in[7];
  float* out = (float*)d_out;

  const int N = in_sizes[0] / D;   // 100000
  const int E = in_sizes[1] / 2;   // 3200000

  char* wsb = (char*)d_ws;
  auto alloc = [&](size_t elems) {
    char* p = wsb;
    wsb += ((elems * 4 + 255) & ~(size_t)255);
    return p;
  };
  int*   rowptr = (int*)alloc(N + 1);
  int*   cursor = (int*)alloc(N);      // also deg histogram
  int*   part   = (int*)alloc(256);
  float* dinv   = (float*)alloc(N);
  int*   csr    = (int*)alloc(E);
  float* t      = (float*)alloc((size_t)N * D);   // src-scaled transformed features
  float* g1     = (float*)alloc((size_t)N * D);   // h1 (unscaled)

  dim3 b256(256);
  int gN   = (N + 255) / 256;
  int gE   = (E + 255) / 256;
  int gGem = (N + 127) / 128;
  int gAgg = (N + 7) / 8;
  int nparts = (N + 2047) / 2048;

  // ---- CSR build (once; reused by all 3 layers) ----
  int* deg = cursor;
  k_zero_int<<<gN, b256, 0, stream>>>(deg, N);
  k_deg_count<<<gE, b256, 0, stream>>>(ei, deg, E);
  k_scan_part<<<nparts, b256, 0, stream>>>(deg, part, N);
  k_scan_offsets<<<1, b256, 0, stream>>>(part, nparts, rowptr, N);
  k_scan_final<<<nparts, b256, 0, stream>>>(deg, part, rowptr, N);
  k_dinv_cursor<<<gN, b256, 0, stream>>>(rowptr, dinv, cursor, N);
  const int NB = 4;
  int bsz = (N + NB - 1) / NB;
  for (int b = 0; b < NB; b++) {
    int lo = b * bsz;
    int hi = lo + bsz;
    if (hi > N) hi = N;
    k_csr_fill_b<<<gE, b256, 0, stream>>>(ei, cursor, csr, E, lo, hi);
  }

  // ---- layer 0: g1 = relu(Agg(x@W0) + b0) ----
  k_gemm<<<gGem, b256, 0, stream>>>(x, W0, dinv, t, N);
  k_aggregate<0><<<gAgg, b256, 0, stream>>>(rowptr, csr, dinv, t, b0, nullptr, g1, N);

  // ---- layer 1: h2 = relu(Agg(g1@W1) + b1 + g1)  (h2 in d_out) ----
  k_gemm<<<gGem, b256, 0, stream>>>(g1, W1, dinv, t, N);
  k_aggregate<1><<<gAgg, b256, 0, stream>>>(rowptr, csr, dinv, t, b1, g1, out, N);

  // ---- layer 2: out = Agg(h2@W2) + b2 ----
  k_gemm<<<gGem, b256, 0, stream>>>(out, W2, dinv, t, N);
  k_aggregate<2><<<gAgg, b256, 0, stream>>>(rowptr, csr, dinv, t, b2, nullptr, out, N);
}

// Round 7
// 900.102 us; speedup vs baseline: 3.3348x; 1.3844x over previous
//
#include <hip/hip_runtime.h>
#include <hip/hip_fp16.h>

#define D 128
typedef unsigned long long ull;

// ---------------- degree histogram ----------------
__global__ void k_zero_int(int* p, int n) {
  int i = blockIdx.x * blockDim.x + threadIdx.x;
  if (i < n) p[i] = 0;
}

__global__ void k_deg_count(const int* __restrict__ ei, int* __restrict__ deg, int E) {
  int e = blockIdx.x * blockDim.x + threadIdx.x;
  if (e < E) atomicAdd(&deg[ei[E + e]], 1);  // dst row
}

// ---------------- prefix sum (CHUNK = 2048 = 256 threads x 8) ----------------
__global__ void k_scan_part(const int* __restrict__ deg, int* __restrict__ part, int n) {
  __shared__ int sd[256];
  int base = blockIdx.x * 2048 + threadIdx.x * 8;
  int s = 0;
#pragma unroll
  for (int k = 0; k < 8; k++) {
    int idx = base + k;
    if (idx < n) s += deg[idx];
  }
  sd[threadIdx.x] = s;
  __syncthreads();
  for (int off = 128; off > 0; off >>= 1) {
    if (threadIdx.x < off) sd[threadIdx.x] += sd[threadIdx.x + off];
    __syncthreads();
  }
  if (threadIdx.x == 0) part[blockIdx.x] = sd[0];
}

__global__ void k_scan_offsets(int* __restrict__ part, int nparts,
                               int* __restrict__ rowptr, int n) {
  __shared__ int sd[256];
  int v = (threadIdx.x < nparts) ? part[threadIdx.x] : 0;
  sd[threadIdx.x] = v;
  __syncthreads();
  for (int off = 1; off < 256; off <<= 1) {
    int t = (threadIdx.x >= off) ? sd[threadIdx.x - off] : 0;
    __syncthreads();
    sd[threadIdx.x] += t;
    __syncthreads();
  }
  if (threadIdx.x < nparts) part[threadIdx.x] = sd[threadIdx.x] - v;  // exclusive
  if (threadIdx.x == 0) rowptr[n] = sd[255];                          // total = E
}

__global__ void k_scan_final(const int* __restrict__ deg, const int* __restrict__ part,
                             int* __restrict__ rowptr, int n) {
  __shared__ int sd[256];
  int base = blockIdx.x * 2048 + threadIdx.x * 8;
  int loc[8];
  int s = 0;
#pragma unroll
  for (int k = 0; k < 8; k++) {
    int idx = base + k;
    loc[k] = (idx < n) ? deg[idx] : 0;
    s += loc[k];
  }
  sd[threadIdx.x] = s;
  __syncthreads();
  for (int off = 1; off < 256; off <<= 1) {
    int t = (threadIdx.x >= off) ? sd[threadIdx.x - off] : 0;
    __syncthreads();
    sd[threadIdx.x] += t;
    __syncthreads();
  }
  int run = part[blockIdx.x] + sd[threadIdx.x] - s;  // exclusive offset
#pragma unroll
  for (int k = 0; k < 8; k++) {
    int idx = base + k;
    if (idx < n) {
      rowptr[idx] = run;
      run += loc[k];
    }
  }
}

// dinv = rsqrt(in_deg + 1 self-loop); also init cursor = rowptr
__global__ void k_dinv_cursor(const int* __restrict__ rowptr, float* __restrict__ dinv,
                              int* __restrict__ cursor, int n) {
  int i = blockIdx.x * blockDim.x + threadIdx.x;
  if (i < n) {
    int r0 = rowptr[i], r1 = rowptr[i + 1];
    dinv[i] = rsqrtf((float)(r1 - r0) + 1.0f);
    cursor[i] = r0;
  }
}

// bucketed fill: only edges whose dst is in [lo,hi) are placed this pass.
__global__ void k_csr_fill_b(const int* __restrict__ ei, int* __restrict__ cursor,
                             int* __restrict__ csr, int E, int lo, int hi) {
  int e = blockIdx.x * blockDim.x + threadIdx.x;
  if (e >= E) return;
  int d = __builtin_nontemporal_load(&ei[E + e]);
  if (d < lo || d >= hi) return;
  int s = __builtin_nontemporal_load(&ei[e]);
  int pos = atomicAdd(&cursor[d], 1);
  csr[pos] = s;
}

// ---------------- GEMM: Th[n,128](fp16) = (A[n,128] @ W[128,128]) * dinv[row] ----------------
// A staged transposed in LDS (66 KB -> 2 blocks/CU); W read via L1/L2.
__launch_bounds__(256, 2)
__global__ void k_gemm(const float* __restrict__ A, const float* __restrict__ W,
                       const float* __restrict__ dinv, __half* __restrict__ Th, int n) {
  __shared__ float As[D * 129];     // [k][row] transposed, pad 129
  const int tid = threadIdx.x;
  const int row0 = blockIdx.x * 128;

  for (int i = tid; i < 128 * 32; i += 256) {
    int r = i >> 5;
    int k4 = (i & 31) << 2;
    int gr = row0 + r;
    float4 v = make_float4(0.f, 0.f, 0.f, 0.f);
    if (gr < n) v = ((const float4*)A)[(size_t)gr * 32 + (i & 31)];
    As[(k4 + 0) * 129 + r] = v.x;
    As[(k4 + 1) * 129 + r] = v.y;
    As[(k4 + 2) * 129 + r] = v.z;
    As[(k4 + 3) * 129 + r] = v.w;
  }
  __syncthreads();

  const int tx = tid & 15;
  const int ty = tid >> 4;
  const int c0 = tx * 4;
  const int r0 = ty * 4;

  float acc[8][8];
#pragma unroll
  for (int i = 0; i < 8; i++)
#pragma unroll
    for (int j = 0; j < 8; j++) acc[i][j] = 0.f;

#pragma unroll 4
  for (int k = 0; k < D; k++) {
    float4 a0 = *(const float4*)&As[k * 129 + r0];
    float4 a1 = *(const float4*)&As[k * 129 + r0 + 64];
    float4 w0 = *(const float4*)&W[k * D + c0];        // L1/L2 hit
    float4 w1 = *(const float4*)&W[k * D + c0 + 64];
    float av[8] = {a0.x, a0.y, a0.z, a0.w, a1.x, a1.y, a1.z, a1.w};
    float wv[8] = {w0.x, w0.y, w0.z, w0.w, w1.x, w1.y, w1.z, w1.w};
#pragma unroll
    for (int i = 0; i < 8; i++)
#pragma unroll
      for (int j = 0; j < 8; j++) acc[i][j] = fmaf(av[i], wv[j], acc[i][j]);
  }

#pragma unroll
  for (int i = 0; i < 8; i++) {
    int gr = row0 + r0 + (i & 3) + (i >> 2) * 64;
    if (gr < n) {
      float sc = dinv[gr];   // fold src-side norm into rows
      union { __half2 h[2]; uint2 u; } p0, p1;
      p0.h[0] = __floats2half2_rn(acc[i][0] * sc, acc[i][1] * sc);
      p0.h[1] = __floats2half2_rn(acc[i][2] * sc, acc[i][3] * sc);
      p1.h[0] = __floats2half2_rn(acc[i][4] * sc, acc[i][5] * sc);
      p1.h[1] = __floats2half2_rn(acc[i][6] * sc, acc[i][7] * sc);
      *(uint2*)&Th[(size_t)gr * D + c0] = p0.u;
      *(uint2*)&Th[(size_t)gr * D + c0 + 64] = p1.u;
    }
  }
}

// ---------------- pull-style aggregation (fp16 gathers) ----------------
// th pre-scaled by dinv[row]:  out[d] = dinv[d]*(th[d] + sum th[src]) + b  [+res] [relu]
// 16 lanes per node (lane owns 8 cols = 16B fp16), 4 nodes per wave.
// MODE 0: relu; MODE 1: relu(+res); MODE 2: raw
template <int MODE>
__launch_bounds__(256)
__global__ void k_aggregate(const int* __restrict__ rowptr, const int* __restrict__ csr,
                            const float* __restrict__ dinv, const __half* __restrict__ th,
                            const float* __restrict__ b, const float* __restrict__ res,
                            float* __restrict__ out, int n) {
  int node = blockIdx.x * 16 + (threadIdx.x >> 4);
  if (node >= n) return;
  const int l16 = threadIdx.x & 15;

  int beg = rowptr[node];
  int end = rowptr[node + 1];
  float dd = dinv[node];

  const float4* t4 = (const float4*)th;   // float4 = 8 halves = 16B

  float a0, a1, a2, a3, a4, a5, a6, a7;
  {
    float4 raw = t4[(size_t)node * 16 + l16];   // self term
    const __half2* hp = (const __half2*)&raw;
    float2 f0 = __half22float2(hp[0]);
    float2 f1 = __half22float2(hp[1]);
    float2 f2 = __half22float2(hp[2]);
    float2 f3 = __half22float2(hp[3]);
    a0 = f0.x; a1 = f0.y; a2 = f1.x; a3 = f1.y;
    a4 = f2.x; a5 = f2.y; a6 = f3.x; a7 = f3.y;
  }

#define ACC_ROW(raw)                                  \
  {                                                   \
    const __half2* hp = (const __half2*)&(raw);       \
    float2 f0 = __half22float2(hp[0]);                \
    float2 f1 = __half22float2(hp[1]);                \
    float2 f2 = __half22float2(hp[2]);                \
    float2 f3 = __half22float2(hp[3]);                \
    a0 += f0.x; a1 += f0.y; a2 += f1.x; a3 += f1.y;   \
    a4 += f2.x; a5 += f2.y; a6 += f3.x; a7 += f3.y;   \
  }

  int j = beg;
  for (; j + 4 <= end; j += 4) {
    int s0 = __builtin_nontemporal_load(&csr[j + 0]);
    int s1 = __builtin_nontemporal_load(&csr[j + 1]);
    int s2 = __builtin_nontemporal_load(&csr[j + 2]);
    int s3 = __builtin_nontemporal_load(&csr[j + 3]);
    float4 r0 = t4[(size_t)(unsigned)s0 * 16 + l16];
    float4 r1 = t4[(size_t)(unsigned)s1 * 16 + l16];
    float4 r2 = t4[(size_t)(unsigned)s2 * 16 + l16];
    float4 r3 = t4[(size_t)(unsigned)s3 * 16 + l16];
    ACC_ROW(r0) ACC_ROW(r1) ACC_ROW(r2) ACC_ROW(r3)
  }
  for (; j < end; ++j) {
    int s = __builtin_nontemporal_load(&csr[j]);
    float4 r = t4[(size_t)(unsigned)s * 16 + l16];
    ACC_ROW(r)
  }
#undef ACC_ROW

  const float4* b4 = (const float4*)b;
  float4 bb0 = b4[l16 * 2];
  float4 bb1 = b4[l16 * 2 + 1];
  float4 o0, o1;
  o0.x = fmaf(a0, dd, bb0.x); o0.y = fmaf(a1, dd, bb0.y);
  o0.z = fmaf(a2, dd, bb0.z); o0.w = fmaf(a3, dd, bb0.w);
  o1.x = fmaf(a4, dd, bb1.x); o1.y = fmaf(a5, dd, bb1.y);
  o1.z = fmaf(a6, dd, bb1.z); o1.w = fmaf(a7, dd, bb1.w);

  if (MODE == 1) {
    float4 rr0 = ((const float4*)res)[(size_t)node * 32 + l16 * 2];
    float4 rr1 = ((const float4*)res)[(size_t)node * 32 + l16 * 2 + 1];
    o0.x += rr0.x; o0.y += rr0.y; o0.z += rr0.z; o0.w += rr0.w;
    o1.x += rr1.x; o1.y += rr1.y; o1.z += rr1.z; o1.w += rr1.w;
  }
  if (MODE == 0 || MODE == 1) {
    o0.x = fmaxf(o0.x, 0.f); o0.y = fmaxf(o0.y, 0.f);
    o0.z = fmaxf(o0.z, 0.f); o0.w = fmaxf(o0.w, 0.f);
    o1.x = fmaxf(o1.x, 0.f); o1.y = fmaxf(o1.y, 0.f);
    o1.z = fmaxf(o1.z, 0.f); o1.w = fmaxf(o1.w, 0.f);
  }
  ((float4*)out)[(size_t)node * 32 + l16 * 2] = o0;
  ((float4*)out)[(size_t)node * 32 + l16 * 2 + 1] = o1;
}

extern "C" void kernel_launch(void* const* d_in, const int* in_sizes, int n_in,
                              void* d_out, int out_size, void* d_ws, size_t ws_size,
                              hipStream_t stream) {
  const float* x  = (const float*)d_in[0];
  const int*   ei = (const int*)d_in[1];
  const float* W0 = (const float*)d_in[2];
  const float* b0 = (const float*)d_in[3];
  const float* W1 = (const float*)d_in[4];
  const float* b1 = (const float*)d_in[5];
  const float* W2 = (const float*)d_in[6];
  const float* b2 = (const float*)d_in[7];
  float* out = (float*)d_out;

  const int N = in_sizes[0] / D;   // 100000
  const int E = in_sizes[1] / 2;   // 3200000

  char* wsb = (char*)d_ws;
  auto alloc = [&](size_t bytes) {
    char* p = wsb;
    wsb += ((bytes + 255) & ~(size_t)255);
    return p;
  };
  int*    rowptr = (int*)alloc((N + 1) * 4);
  int*    cursor = (int*)alloc(N * 4);      // also deg histogram
  int*    part   = (int*)alloc(256 * 4);
  float*  dinv   = (float*)alloc(N * 4);
  int*    csr    = (int*)alloc((size_t)E * 4);
  __half* th     = (__half*)alloc((size_t)N * D * 2);   // fp16 src-scaled features
  float*  g1     = (float*)alloc((size_t)N * D * 4);    // h1 (f32)

  dim3 b256(256);
  int gN   = (N + 255) / 256;
  int gE   = (E + 255) / 256;
  int gGem = (N + 127) / 128;
  int gAgg = (N + 15) / 16;
  int nparts = (N + 2047) / 2048;

  // ---- CSR build (once; reused by all 3 layers) ----
  int* deg = cursor;
  k_zero_int<<<gN, b256, 0, stream>>>(deg, N);
  k_deg_count<<<gE, b256, 0, stream>>>(ei, deg, E);
  k_scan_part<<<nparts, b256, 0, stream>>>(deg, part, N);
  k_scan_offsets<<<1, b256, 0, stream>>>(part, nparts, rowptr, N);
  k_scan_final<<<nparts, b256, 0, stream>>>(deg, part, rowptr, N);
  k_dinv_cursor<<<gN, b256, 0, stream>>>(rowptr, dinv, cursor, N);
  const int NB = 4;
  int bsz = (N + NB - 1) / NB;
  for (int b = 0; b < NB; b++) {
    int lo = b * bsz;
    int hi = lo + bsz;
    if (hi > N) hi = N;
    k_csr_fill_b<<<gE, b256, 0, stream>>>(ei, cursor, csr, E, lo, hi);
  }

  // ---- layer 0: g1 = relu(Agg(x@W0) + b0) ----
  k_gemm<<<gGem, b256, 0, stream>>>(x, W0, dinv, th, N);
  k_aggregate<0><<<gAgg, b256, 0, stream>>>(rowptr, csr, dinv, th, b0, nullptr, g1, N);

  // ---- layer 1: h2 = relu(Agg(g1@W1) + b1 + g1)  (h2 in d_out) ----
  k_gemm<<<gGem, b256, 0, stream>>>(g1, W1, dinv, th, N);
  k_aggregate<1><<<gAgg, b256, 0, stream>>>(rowptr, csr, dinv, th, b1, g1, out, N);

  // ---- layer 2: out = Agg(h2@W2) + b2 ----
  k_gemm<<<gGem, b256, 0, stream>>>(out, W2, dinv, th, N);
  k_aggregate<2><<<gAgg, b256, 0, stream>>>(rowptr, csr, dinv, th, b2, nullptr, out, N);
}

// Round 8
// 850.523 us; speedup vs baseline: 3.5292x; 1.0583x over previous
//
#include <hip/hip_runtime.h>
#include <hip/hip_fp16.h>

#define D 128
typedef unsigned long long ull;
typedef _Float16 half8 __attribute__((ext_vector_type(8)));
typedef _Float16 half4v __attribute__((ext_vector_type(4)));
typedef float f32x4 __attribute__((ext_vector_type(4)));

// ---------------- degree histogram ----------------
__global__ void k_zero_int(int* p, int n) {
  int i = blockIdx.x * blockDim.x + threadIdx.x;
  if (i < n) p[i] = 0;
}

__global__ void k_deg_count(const int* __restrict__ ei, int* __restrict__ deg, int E) {
  int e = blockIdx.x * blockDim.x + threadIdx.x;
  if (e < E) atomicAdd(&deg[ei[E + e]], 1);  // dst row
}

// ---------------- prefix sum (CHUNK = 2048 = 256 threads x 8) ----------------
__global__ void k_scan_part(const int* __restrict__ deg, int* __restrict__ part, int n) {
  __shared__ int sd[256];
  int base = blockIdx.x * 2048 + threadIdx.x * 8;
  int s = 0;
#pragma unroll
  for (int k = 0; k < 8; k++) {
    int idx = base + k;
    if (idx < n) s += deg[idx];
  }
  sd[threadIdx.x] = s;
  __syncthreads();
  for (int off = 128; off > 0; off >>= 1) {
    if (threadIdx.x < off) sd[threadIdx.x] += sd[threadIdx.x + off];
    __syncthreads();
  }
  if (threadIdx.x == 0) part[blockIdx.x] = sd[0];
}

__global__ void k_scan_offsets(int* __restrict__ part, int nparts,
                               int* __restrict__ rowptr, int n) {
  __shared__ int sd[256];
  int v = (threadIdx.x < nparts) ? part[threadIdx.x] : 0;
  sd[threadIdx.x] = v;
  __syncthreads();
  for (int off = 1; off < 256; off <<= 1) {
    int t = (threadIdx.x >= off) ? sd[threadIdx.x - off] : 0;
    __syncthreads();
    sd[threadIdx.x] += t;
    __syncthreads();
  }
  if (threadIdx.x < nparts) part[threadIdx.x] = sd[threadIdx.x] - v;  // exclusive
  if (threadIdx.x == 0) rowptr[n] = sd[255];                          // total = E
}

__global__ void k_scan_final(const int* __restrict__ deg, const int* __restrict__ part,
                             int* __restrict__ rowptr, int n) {
  __shared__ int sd[256];
  int base = blockIdx.x * 2048 + threadIdx.x * 8;
  int loc[8];
  int s = 0;
#pragma unroll
  for (int k = 0; k < 8; k++) {
    int idx = base + k;
    loc[k] = (idx < n) ? deg[idx] : 0;
    s += loc[k];
  }
  sd[threadIdx.x] = s;
  __syncthreads();
  for (int off = 1; off < 256; off <<= 1) {
    int t = (threadIdx.x >= off) ? sd[threadIdx.x - off] : 0;
    __syncthreads();
    sd[threadIdx.x] += t;
    __syncthreads();
  }
  int run = part[blockIdx.x] + sd[threadIdx.x] - s;  // exclusive offset
#pragma unroll
  for (int k = 0; k < 8; k++) {
    int idx = base + k;
    if (idx < n) {
      rowptr[idx] = run;
      run += loc[k];
    }
  }
}

// dinv = rsqrt(in_deg + 1 self-loop); also init cursor = rowptr
__global__ void k_dinv_cursor(const int* __restrict__ rowptr, float* __restrict__ dinv,
                              int* __restrict__ cursor, int n) {
  int i = blockIdx.x * blockDim.x + threadIdx.x;
  if (i < n) {
    int r0 = rowptr[i], r1 = rowptr[i + 1];
    dinv[i] = rsqrtf((float)(r1 - r0) + 1.0f);
    cursor[i] = r0;
  }
}

// bucketed fill: only edges whose dst is in [lo,hi) are placed this pass.
__global__ void k_csr_fill_b(const int* __restrict__ ei, int* __restrict__ cursor,
                             int* __restrict__ csr, int E, int lo, int hi) {
  int e = blockIdx.x * blockDim.x + threadIdx.x;
  if (e >= E) return;
  int d = __builtin_nontemporal_load(&ei[E + e]);
  if (d < lo || d >= hi) return;
  int s = __builtin_nontemporal_load(&ei[e]);
  int pos = atomicAdd(&cursor[d], 1);
  csr[pos] = s;
}

// ---------------- MFMA GEMM: Th[n,128](fp16) = (A[n,128] @ W[128,128]) * dinv[row] ----
// mfma_f32_16x16x32_f16. 128x128 tile, 4 waves; wave w: rows w*32..w*32+31, all 128 cols.
// Fragment layout: lane l (g=l>>4, q=l&15): A[row=q][k] / B[k][col=q] with the 8 halves
// covering k = {4g..4g+3} u {16+4g..16+4g+3} per 32-k step (two stacked 16x16x16).
// LDS stores k PERMUTED: step-local k=4g+e -> pos 8g+e, k=16+4g+e -> pos 8g+4+e, so a
// fragment is ONE ds_read_b128. Row stride 136 halves (272B) -> 2-way bank alias (free).
__launch_bounds__(256, 2)
__global__ void k_gemm_mfma(const float* __restrict__ A, const float* __restrict__ W,
                            const float* __restrict__ dinv, __half* __restrict__ Th, int n) {
  __shared__ _Float16 Al[128 * 136];
  __shared__ _Float16 Bl[128 * 136];
  const int tid = threadIdx.x;
  const int row0 = blockIdx.x * 128;

  // k-permutation for a 4-aligned k quartet k4 within full K=128:
  //   kt=k4>>5, k32=k4&31, pos = kt*32 + ((k32&15)>>2)*8 + (k32>>4)*4
  // stage A: i -> (r = i>>5, k4 = (i&31)*4); coalesced float4 row reads
  for (int i = tid; i < 4096; i += 256) {
    int r = i >> 5;
    int k4 = (i & 31) << 2;
    float4 v = make_float4(0.f, 0.f, 0.f, 0.f);
    if (row0 + r < n) v = ((const float4*)A)[(size_t)(row0 + r) * 32 + (i & 31)];
    int pos = (k4 & ~31) + (((k4 & 15) >> 2) << 3) + ((k4 >> 4) & 1) * 4;
    *(half4v*)&Al[r * 136 + pos] =
        (half4v){(_Float16)v.x, (_Float16)v.y, (_Float16)v.z, (_Float16)v.w};
  }
  // stage W transposed: i -> (c = i&127, k4 = (i>>7)*4); consecutive tid = consecutive c
  for (int i = tid; i < 4096; i += 256) {
    int c = i & 127;
    int k4 = (i >> 7) << 2;
    float w0 = W[(k4 + 0) * D + c];
    float w1 = W[(k4 + 1) * D + c];
    float w2 = W[(k4 + 2) * D + c];
    float w3 = W[(k4 + 3) * D + c];
    int pos = (k4 & ~31) + (((k4 & 15) >> 2) << 3) + ((k4 >> 4) & 1) * 4;
    *(half4v*)&Bl[c * 136 + pos] =
        (half4v){(_Float16)w0, (_Float16)w1, (_Float16)w2, (_Float16)w3};
  }
  __syncthreads();

  const int w = tid >> 6;
  const int lane = tid & 63;
  const int g = lane >> 4;
  const int q = lane & 15;

  f32x4 acc[2][8];
#pragma unroll
  for (int mt = 0; mt < 2; mt++)
#pragma unroll
    for (int nt = 0; nt < 8; nt++) acc[mt][nt] = (f32x4){0.f, 0.f, 0.f, 0.f};

#pragma unroll
  for (int kt = 0; kt < 4; kt++) {
    half8 a[2], b[8];
#pragma unroll
    for (int mt = 0; mt < 2; mt++)
      a[mt] = *(const half8*)&Al[(w * 32 + mt * 16 + q) * 136 + kt * 32 + g * 8];
#pragma unroll
    for (int nt = 0; nt < 8; nt++)
      b[nt] = *(const half8*)&Bl[(nt * 16 + q) * 136 + kt * 32 + g * 8];
#pragma unroll
    for (int mt = 0; mt < 2; mt++)
#pragma unroll
      for (int nt = 0; nt < 8; nt++)
        acc[mt][nt] = __builtin_amdgcn_mfma_f32_16x16x32_f16(a[mt], b[nt], acc[mt][nt], 0, 0, 0);
  }

  // epilogue: D[row=4g+r][col=q] per tile; scale by dinv[row], store fp16
#pragma unroll
  for (int mt = 0; mt < 2; mt++) {
    int baseRow = row0 + w * 32 + mt * 16 + g * 4;
    float dv[4];
#pragma unroll
    for (int r = 0; r < 4; r++) dv[r] = (baseRow + r < n) ? dinv[baseRow + r] : 0.f;
#pragma unroll
    for (int nt = 0; nt < 8; nt++) {
      int col = nt * 16 + q;
#pragma unroll
      for (int r = 0; r < 4; r++) {
        int gr = baseRow + r;
        if (gr < n) Th[(size_t)gr * D + col] = (__half)(acc[mt][nt][r] * dv[r]);
      }
    }
  }
}

// ---------------- pull-style aggregation (fp16 gathers) ----------------
// th pre-scaled by dinv[row]:  out[d] = dinv[d]*(th[d] + sum th[src]) + b  [+res] [relu]
// 16 lanes per node (lane owns 8 cols = 16B fp16), 4 nodes per wave.
// MODE 0: relu; MODE 1: relu(+res); MODE 2: raw
template <int MODE>
__launch_bounds__(256)
__global__ void k_aggregate(const int* __restrict__ rowptr, const int* __restrict__ csr,
                            const float* __restrict__ dinv, const __half* __restrict__ th,
                            const float* __restrict__ b, const float* __restrict__ res,
                            float* __restrict__ out, int n) {
  int node = blockIdx.x * 16 + (threadIdx.x >> 4);
  if (node >= n) return;
  const int l16 = threadIdx.x & 15;

  int beg = rowptr[node];
  int end = rowptr[node + 1];
  float dd = dinv[node];

  const float4* t4 = (const float4*)th;   // float4 = 8 halves = 16B

  float a0, a1, a2, a3, a4, a5, a6, a7;
  {
    float4 raw = t4[(size_t)node * 16 + l16];   // self term
    const __half2* hp = (const __half2*)&raw;
    float2 f0 = __half22float2(hp[0]);
    float2 f1 = __half22float2(hp[1]);
    float2 f2 = __half22float2(hp[2]);
    float2 f3 = __half22float2(hp[3]);
    a0 = f0.x; a1 = f0.y; a2 = f1.x; a3 = f1.y;
    a4 = f2.x; a5 = f2.y; a6 = f3.x; a7 = f3.y;
  }

#define ACC_ROW(raw)                                  \
  {                                                   \
    const __half2* hp = (const __half2*)&(raw);       \
    float2 f0 = __half22float2(hp[0]);                \
    float2 f1 = __half22float2(hp[1]);                \
    float2 f2 = __half22float2(hp[2]);                \
    float2 f3 = __half22float2(hp[3]);                \
    a0 += f0.x; a1 += f0.y; a2 += f1.x; a3 += f1.y;   \
    a4 += f2.x; a5 += f2.y; a6 += f3.x; a7 += f3.y;   \
  }

  int j = beg;
  for (; j + 4 <= end; j += 4) {
    int s0 = __builtin_nontemporal_load(&csr[j + 0]);
    int s1 = __builtin_nontemporal_load(&csr[j + 1]);
    int s2 = __builtin_nontemporal_load(&csr[j + 2]);
    int s3 = __builtin_nontemporal_load(&csr[j + 3]);
    float4 r0 = t4[(size_t)(unsigned)s0 * 16 + l16];
    float4 r1 = t4[(size_t)(unsigned)s1 * 16 + l16];
    float4 r2 = t4[(size_t)(unsigned)s2 * 16 + l16];
    float4 r3 = t4[(size_t)(unsigned)s3 * 16 + l16];
    ACC_ROW(r0) ACC_ROW(r1) ACC_ROW(r2) ACC_ROW(r3)
  }
  for (; j < end; ++j) {
    int s = __builtin_nontemporal_load(&csr[j]);
    float4 r = t4[(size_t)(unsigned)s * 16 + l16];
    ACC_ROW(r)
  }
#undef ACC_ROW

  const float4* b4 = (const float4*)b;
  float4 bb0 = b4[l16 * 2];
  float4 bb1 = b4[l16 * 2 + 1];
  float4 o0, o1;
  o0.x = fmaf(a0, dd, bb0.x); o0.y = fmaf(a1, dd, bb0.y);
  o0.z = fmaf(a2, dd, bb0.z); o0.w = fmaf(a3, dd, bb0.w);
  o1.x = fmaf(a4, dd, bb1.x); o1.y = fmaf(a5, dd, bb1.y);
  o1.z = fmaf(a6, dd, bb1.z); o1.w = fmaf(a7, dd, bb1.w);

  if (MODE == 1) {
    float4 rr0 = ((const float4*)res)[(size_t)node * 32 + l16 * 2];
    float4 rr1 = ((const float4*)res)[(size_t)node * 32 + l16 * 2 + 1];
    o0.x += rr0.x; o0.y += rr0.y; o0.z += rr0.z; o0.w += rr0.w;
    o1.x += rr1.x; o1.y += rr1.y; o1.z += rr1.z; o1.w += rr1.w;
  }
  if (MODE == 0 || MODE == 1) {
    o0.x = fmaxf(o0.x, 0.f); o0.y = fmaxf(o0.y, 0.f);
    o0.z = fmaxf(o0.z, 0.f); o0.w = fmaxf(o0.w, 0.f);
    o1.x = fmaxf(o1.x, 0.f); o1.y = fmaxf(o1.y, 0.f);
    o1.z = fmaxf(o1.z, 0.f); o1.w = fmaxf(o1.w, 0.f);
  }
  ((float4*)out)[(size_t)node * 32 + l16 * 2] = o0;
  ((float4*)out)[(size_t)node * 32 + l16 * 2 + 1] = o1;
}

extern "C" void kernel_launch(void* const* d_in, const int* in_sizes, int n_in,
                              void* d_out, int out_size, void* d_ws, size_t ws_size,
                              hipStream_t stream) {
  const float* x  = (const float*)d_in[0];
  const int*   ei = (const int*)d_in[1];
  const float* W0 = (const float*)d_in[2];
  const float* b0 = (const float*)d_in[3];
  const float* W1 = (const float*)d_in[4];
  const float* b1 = (const float*)d_in[5];
  const float* W2 = (const float*)d_in[6];
  const float* b2 = (const float*)d_in[7];
  float* out = (float*)d_out;

  const int N = in_sizes[0] / D;   // 100000
  const int E = in_sizes[1] / 2;   // 3200000

  char* wsb = (char*)d_ws;
  auto alloc = [&](size_t bytes) {
    char* p = wsb;
    wsb += ((bytes + 255) & ~(size_t)255);
    return p;
  };
  int*    rowptr = (int*)alloc((N + 1) * 4);
  int*    cursor = (int*)alloc(N * 4);      // also deg histogram
  int*    part   = (int*)alloc(256 * 4);
  float*  dinv   = (float*)alloc(N * 4);
  int*    csr    = (int*)alloc((size_t)E * 4);
  __half* th     = (__half*)alloc((size_t)N * D * 2);   // fp16 src-scaled features
  float*  g1     = (float*)alloc((size_t)N * D * 4);    // h1 (f32)

  dim3 b256(256);
  int gN   = (N + 255) / 256;
  int gE   = (E + 255) / 256;
  int gGem = (N + 127) / 128;
  int gAgg = (N + 15) / 16;
  int nparts = (N + 2047) / 2048;

  // ---- CSR build (once; reused by all 3 layers) ----
  int* deg = cursor;
  k_zero_int<<<gN, b256, 0, stream>>>(deg, N);
  k_deg_count<<<gE, b256, 0, stream>>>(ei, deg, E);
  k_scan_part<<<nparts, b256, 0, stream>>>(deg, part, N);
  k_scan_offsets<<<1, b256, 0, stream>>>(part, nparts, rowptr, N);
  k_scan_final<<<nparts, b256, 0, stream>>>(deg, part, rowptr, N);
  k_dinv_cursor<<<gN, b256, 0, stream>>>(rowptr, dinv, cursor, N);
  const int NB = 4;
  int bsz = (N + NB - 1) / NB;
  for (int b = 0; b < NB; b++) {
    int lo = b * bsz;
    int hi = lo + bsz;
    if (hi > N) hi = N;
    k_csr_fill_b<<<gE, b256, 0, stream>>>(ei, cursor, csr, E, lo, hi);
  }

  // ---- layer 0: g1 = relu(Agg(x@W0) + b0) ----
  k_gemm_mfma<<<gGem, b256, 0, stream>>>(x, W0, dinv, th, N);
  k_aggregate<0><<<gAgg, b256, 0, stream>>>(rowptr, csr, dinv, th, b0, nullptr, g1, N);

  // ---- layer 1: h2 = relu(Agg(g1@W1) + b1 + g1)  (h2 in d_out) ----
  k_gemm_mfma<<<gGem, b256, 0, stream>>>(g1, W1, dinv, th, N);
  k_aggregate<1><<<gAgg, b256, 0, stream>>>(rowptr, csr, dinv, th, b1, g1, out, N);

  // ---- layer 2: out = Agg(h2@W2) + b2 ----
  k_gemm_mfma<<<gGem, b256, 0, stream>>>(out, W2, dinv, th, N);
  k_aggregate<2><<<gAgg, b256, 0, stream>>>(rowptr, csr, dinv, th, b2, nullptr, out, N);
}

// Round 9
// 814.159 us; speedup vs baseline: 3.6868x; 1.0447x over previous
//
#include <hip/hip_runtime.h>
#include <hip/hip_fp16.h>

#define D 128
typedef unsigned long long ull;
typedef _Float16 half8 __attribute__((ext_vector_type(8)));
typedef _Float16 half4v __attribute__((ext_vector_type(4)));
typedef float f32x4 __attribute__((ext_vector_type(4)));

// k-permutation: quartet k4 -> LDS pos so each MFMA fragment is one ds_read_b128
#define KPOS(k4) (((k4) & ~31) + ((((k4) & 15) >> 2) << 3) + ((((k4) >> 4) & 1) << 2))

// ---------------- degree histogram ----------------
__global__ void k_zero_int(int* p, int n) {
  int i = blockIdx.x * blockDim.x + threadIdx.x;
  if (i < n) p[i] = 0;
}

__global__ void k_deg_count(const int* __restrict__ ei, int* __restrict__ deg, int E) {
  int e = blockIdx.x * blockDim.x + threadIdx.x;
  if (e < E) atomicAdd(&deg[ei[E + e]], 1);  // dst row
}

// ---------------- prefix sum (CHUNK = 2048 = 256 threads x 8) ----------------
__global__ void k_scan_part(const int* __restrict__ deg, int* __restrict__ part, int n) {
  __shared__ int sd[256];
  int base = blockIdx.x * 2048 + threadIdx.x * 8;
  int s = 0;
#pragma unroll
  for (int k = 0; k < 8; k++) {
    int idx = base + k;
    if (idx < n) s += deg[idx];
  }
  sd[threadIdx.x] = s;
  __syncthreads();
  for (int off = 128; off > 0; off >>= 1) {
    if (threadIdx.x < off) sd[threadIdx.x] += sd[threadIdx.x + off];
    __syncthreads();
  }
  if (threadIdx.x == 0) part[blockIdx.x] = sd[0];
}

__global__ void k_scan_offsets(int* __restrict__ part, int nparts,
                               int* __restrict__ rowptr, int n) {
  __shared__ int sd[256];
  int v = (threadIdx.x < nparts) ? part[threadIdx.x] : 0;
  sd[threadIdx.x] = v;
  __syncthreads();
  for (int off = 1; off < 256; off <<= 1) {
    int t = (threadIdx.x >= off) ? sd[threadIdx.x - off] : 0;
    __syncthreads();
    sd[threadIdx.x] += t;
    __syncthreads();
  }
  if (threadIdx.x < nparts) part[threadIdx.x] = sd[threadIdx.x] - v;  // exclusive
  if (threadIdx.x == 0) rowptr[n] = sd[255];                          // total = E
}

__global__ void k_scan_final(const int* __restrict__ deg, const int* __restrict__ part,
                             int* __restrict__ rowptr, int n) {
  __shared__ int sd[256];
  int base = blockIdx.x * 2048 + threadIdx.x * 8;
  int loc[8];
  int s = 0;
#pragma unroll
  for (int k = 0; k < 8; k++) {
    int idx = base + k;
    loc[k] = (idx < n) ? deg[idx] : 0;
    s += loc[k];
  }
  sd[threadIdx.x] = s;
  __syncthreads();
  for (int off = 1; off < 256; off <<= 1) {
    int t = (threadIdx.x >= off) ? sd[threadIdx.x - off] : 0;
    __syncthreads();
    sd[threadIdx.x] += t;
    __syncthreads();
  }
  int run = part[blockIdx.x] + sd[threadIdx.x] - s;  // exclusive offset
#pragma unroll
  for (int k = 0; k < 8; k++) {
    int idx = base + k;
    if (idx < n) {
      rowptr[idx] = run;
      run += loc[k];
    }
  }
}

// dinv = rsqrt(in_deg + 1 self-loop); also init cursor = rowptr
__global__ void k_dinv_cursor(const int* __restrict__ rowptr, float* __restrict__ dinv,
                              int* __restrict__ cursor, int n) {
  int i = blockIdx.x * blockDim.x + threadIdx.x;
  if (i < n) {
    int r0 = rowptr[i], r1 = rowptr[i + 1];
    dinv[i] = rsqrtf((float)(r1 - r0) + 1.0f);
    cursor[i] = r0;
  }
}

// bucketed fill: only edges whose dst is in [lo,hi) are placed this pass.
__global__ void k_csr_fill_b(const int* __restrict__ ei, int* __restrict__ cursor,
                             int* __restrict__ csr, int E, int lo, int hi) {
  int e = blockIdx.x * blockDim.x + threadIdx.x;
  if (e >= E) return;
  int d = __builtin_nontemporal_load(&ei[E + e]);
  if (d < lo || d >= hi) return;
  int s = __builtin_nontemporal_load(&ei[e]);
  int pos = atomicAdd(&cursor[d], 1);
  csr[pos] = s;
}

// ---------------- MFMA GEMM: Th[n,128](fp16) = (A[n,128] @ W[128,128]) * dinv[row] ----
// mfma_f32_16x16x32_f16, 128x128 tile, 4 waves. A input f32 (HALF_IN=0) or fp16 (HALF_IN=1).
template <int HALF_IN>
__launch_bounds__(256, 2)
__global__ void k_gemm_mfma(const void* __restrict__ Av, const float* __restrict__ W,
                            const float* __restrict__ dinv, __half* __restrict__ Th, int n) {
  __shared__ _Float16 Al[128 * 136];
  __shared__ _Float16 Bl[128 * 136];
  const int tid = threadIdx.x;
  const int row0 = blockIdx.x * 128;

  if (HALF_IN) {
    const _Float16* A = (const _Float16*)Av;
    for (int i = tid; i < 2048; i += 256) {   // 128 rows x 16 chunks of 8 halves
      int r = i >> 4;
      int k8 = (i & 15) << 3;
      half8 v = {0, 0, 0, 0, 0, 0, 0, 0};
      if (row0 + r < n) v = *(const half8*)&A[(size_t)(row0 + r) * D + k8];
      *(half4v*)&Al[r * 136 + KPOS(k8)]     = (half4v){v[0], v[1], v[2], v[3]};
      *(half4v*)&Al[r * 136 + KPOS(k8 + 4)] = (half4v){v[4], v[5], v[6], v[7]};
    }
  } else {
    const float* A = (const float*)Av;
    for (int i = tid; i < 4096; i += 256) {
      int r = i >> 5;
      int k4 = (i & 31) << 2;
      float4 v = make_float4(0.f, 0.f, 0.f, 0.f);
      if (row0 + r < n) v = ((const float4*)A)[(size_t)(row0 + r) * 32 + (i & 31)];
      *(half4v*)&Al[r * 136 + KPOS(k4)] =
          (half4v){(_Float16)v.x, (_Float16)v.y, (_Float16)v.z, (_Float16)v.w};
    }
  }
  // stage W transposed: consecutive tid = consecutive c (coalesced)
  for (int i = tid; i < 4096; i += 256) {
    int c = i & 127;
    int k4 = (i >> 7) << 2;
    float w0 = W[(k4 + 0) * D + c];
    float w1 = W[(k4 + 1) * D + c];
    float w2 = W[(k4 + 2) * D + c];
    float w3 = W[(k4 + 3) * D + c];
    *(half4v*)&Bl[c * 136 + KPOS(k4)] =
        (half4v){(_Float16)w0, (_Float16)w1, (_Float16)w2, (_Float16)w3};
  }
  __syncthreads();

  const int w = tid >> 6;
  const int lane = tid & 63;
  const int g = lane >> 4;
  const int q = lane & 15;

  f32x4 acc[2][8];
#pragma unroll
  for (int mt = 0; mt < 2; mt++)
#pragma unroll
    for (int nt = 0; nt < 8; nt++) acc[mt][nt] = (f32x4){0.f, 0.f, 0.f, 0.f};

#pragma unroll
  for (int kt = 0; kt < 4; kt++) {
    half8 a[2], b[8];
#pragma unroll
    for (int mt = 0; mt < 2; mt++)
      a[mt] = *(const half8*)&Al[(w * 32 + mt * 16 + q) * 136 + kt * 32 + g * 8];
#pragma unroll
    for (int nt = 0; nt < 8; nt++)
      b[nt] = *(const half8*)&Bl[(nt * 16 + q) * 136 + kt * 32 + g * 8];
#pragma unroll
    for (int mt = 0; mt < 2; mt++)
#pragma unroll
      for (int nt = 0; nt < 8; nt++)
        acc[mt][nt] = __builtin_amdgcn_mfma_f32_16x16x32_f16(a[mt], b[nt], acc[mt][nt], 0, 0, 0);
  }

  // epilogue: D[row=4g+r][col=q] per tile; scale by dinv[row], store fp16
#pragma unroll
  for (int mt = 0; mt < 2; mt++) {
    int baseRow = row0 + w * 32 + mt * 16 + g * 4;
    float dv[4];
#pragma unroll
    for (int r = 0; r < 4; r++) dv[r] = (baseRow + r < n) ? dinv[baseRow + r] : 0.f;
#pragma unroll
    for (int nt = 0; nt < 8; nt++) {
      int col = nt * 16 + q;
#pragma unroll
      for (int r = 0; r < 4; r++) {
        int gr = baseRow + r;
        if (gr < n) Th[(size_t)gr * D + col] = (__half)(acc[mt][nt][r] * dv[r]);
      }
    }
  }
}

// ---------------- pull-style aggregation (fp16 gathers, unroll 8) ----------------
// th pre-scaled by dinv[row]:  acc = dinv[d]*(th[d] + sum th[src]) + b  [+res] [relu]
// 16 lanes per node (lane owns 8 cols = 16B fp16), 4 nodes per wave.
// MODE 0: relu -> fp16 out; MODE 1: relu(+res fp16) -> fp16 out; MODE 2: raw -> f32 out
template <int MODE>
__launch_bounds__(256)
__global__ void k_aggregate(const int* __restrict__ rowptr, const int* __restrict__ csr,
                            const float* __restrict__ dinv, const __half* __restrict__ th,
                            const float* __restrict__ b, const __half* __restrict__ resh,
                            __half* __restrict__ outh, float* __restrict__ outf, int n) {
  int node = blockIdx.x * 16 + (threadIdx.x >> 4);
  if (node >= n) return;
  const int l16 = threadIdx.x & 15;

  int beg = rowptr[node];
  int end = rowptr[node + 1];
  float dd = dinv[node];

  const float4* t4 = (const float4*)th;   // float4 = 8 halves = 16B

  float a0, a1, a2, a3, a4, a5, a6, a7;
  {
    float4 raw = t4[(size_t)node * 16 + l16];   // self term
    const __half2* hp = (const __half2*)&raw;
    float2 f0 = __half22float2(hp[0]);
    float2 f1 = __half22float2(hp[1]);
    float2 f2 = __half22float2(hp[2]);
    float2 f3 = __half22float2(hp[3]);
    a0 = f0.x; a1 = f0.y; a2 = f1.x; a3 = f1.y;
    a4 = f2.x; a5 = f2.y; a6 = f3.x; a7 = f3.y;
  }

#define ACC_ROW(raw)                                  \
  {                                                   \
    const __half2* hp = (const __half2*)&(raw);       \
    float2 f0 = __half22float2(hp[0]);                \
    float2 f1 = __half22float2(hp[1]);                \
    float2 f2 = __half22float2(hp[2]);                \
    float2 f3 = __half22float2(hp[3]);                \
    a0 += f0.x; a1 += f0.y; a2 += f1.x; a3 += f1.y;   \
    a4 += f2.x; a5 += f2.y; a6 += f3.x; a7 += f3.y;   \
  }

  int j = beg;
  for (; j + 8 <= end; j += 8) {
    float4 r0, r1, r2, r3, r4, r5, r6, r7;
    {
      int s0 = __builtin_nontemporal_load(&csr[j + 0]);
      int s1 = __builtin_nontemporal_load(&csr[j + 1]);
      int s2 = __builtin_nontemporal_load(&csr[j + 2]);
      int s3 = __builtin_nontemporal_load(&csr[j + 3]);
      int s4 = __builtin_nontemporal_load(&csr[j + 4]);
      int s5 = __builtin_nontemporal_load(&csr[j + 5]);
      int s6 = __builtin_nontemporal_load(&csr[j + 6]);
      int s7 = __builtin_nontemporal_load(&csr[j + 7]);
      r0 = t4[(size_t)(unsigned)s0 * 16 + l16];
      r1 = t4[(size_t)(unsigned)s1 * 16 + l16];
      r2 = t4[(size_t)(unsigned)s2 * 16 + l16];
      r3 = t4[(size_t)(unsigned)s3 * 16 + l16];
      r4 = t4[(size_t)(unsigned)s4 * 16 + l16];
      r5 = t4[(size_t)(unsigned)s5 * 16 + l16];
      r6 = t4[(size_t)(unsigned)s6 * 16 + l16];
      r7 = t4[(size_t)(unsigned)s7 * 16 + l16];
    }
    ACC_ROW(r0) ACC_ROW(r1) ACC_ROW(r2) ACC_ROW(r3)
    ACC_ROW(r4) ACC_ROW(r5) ACC_ROW(r6) ACC_ROW(r7)
  }
  for (; j + 4 <= end; j += 4) {
    int s0 = __builtin_nontemporal_load(&csr[j + 0]);
    int s1 = __builtin_nontemporal_load(&csr[j + 1]);
    int s2 = __builtin_nontemporal_load(&csr[j + 2]);
    int s3 = __builtin_nontemporal_load(&csr[j + 3]);
    float4 r0 = t4[(size_t)(unsigned)s0 * 16 + l16];
    float4 r1 = t4[(size_t)(unsigned)s1 * 16 + l16];
    float4 r2 = t4[(size_t)(unsigned)s2 * 16 + l16];
    float4 r3 = t4[(size_t)(unsigned)s3 * 16 + l16];
    ACC_ROW(r0) ACC_ROW(r1) ACC_ROW(r2) ACC_ROW(r3)
  }
  for (; j < end; ++j) {
    int s = __builtin_nontemporal_load(&csr[j]);
    float4 r = t4[(size_t)(unsigned)s * 16 + l16];
    ACC_ROW(r)
  }
#undef ACC_ROW

  const float4* b4 = (const float4*)b;
  float4 bb0 = b4[l16 * 2];
  float4 bb1 = b4[l16 * 2 + 1];
  float o0 = fmaf(a0, dd, bb0.x), o1 = fmaf(a1, dd, bb0.y);
  float o2 = fmaf(a2, dd, bb0.z), o3 = fmaf(a3, dd, bb0.w);
  float o4 = fmaf(a4, dd, bb1.x), o5 = fmaf(a5, dd, bb1.y);
  float o6 = fmaf(a6, dd, bb1.z), o7 = fmaf(a7, dd, bb1.w);

  if (MODE == 1) {
    float4 raw = ((const float4*)resh)[(size_t)node * 16 + l16];
    const __half2* hp = (const __half2*)&raw;
    float2 f0 = __half22float2(hp[0]);
    float2 f1 = __half22float2(hp[1]);
    float2 f2 = __half22float2(hp[2]);
    float2 f3 = __half22float2(hp[3]);
    o0 += f0.x; o1 += f0.y; o2 += f1.x; o3 += f1.y;
    o4 += f2.x; o5 += f2.y; o6 += f3.x; o7 += f3.y;
  }
  if (MODE == 0 || MODE == 1) {
    o0 = fmaxf(o0, 0.f); o1 = fmaxf(o1, 0.f); o2 = fmaxf(o2, 0.f); o3 = fmaxf(o3, 0.f);
    o4 = fmaxf(o4, 0.f); o5 = fmaxf(o5, 0.f); o6 = fmaxf(o6, 0.f); o7 = fmaxf(o7, 0.f);
    union { __half2 h[4]; float4 f; } pk;
    pk.h[0] = __floats2half2_rn(o0, o1);
    pk.h[1] = __floats2half2_rn(o2, o3);
    pk.h[2] = __floats2half2_rn(o4, o5);
    pk.h[3] = __floats2half2_rn(o6, o7);
    ((float4*)outh)[(size_t)node * 16 + l16] = pk.f;
  } else {
    ((float4*)outf)[(size_t)node * 32 + l16 * 2] = make_float4(o0, o1, o2, o3);
    ((float4*)outf)[(size_t)node * 32 + l16 * 2 + 1] = make_float4(o4, o5, o6, o7);
  }
}

extern "C" void kernel_launch(void* const* d_in, const int* in_sizes, int n_in,
                              void* d_out, int out_size, void* d_ws, size_t ws_size,
                              hipStream_t stream) {
  const float* x  = (const float*)d_in[0];
  const int*   ei = (const int*)d_in[1];
  const float* W0 = (const float*)d_in[2];
  const float* b0 = (const float*)d_in[3];
  const float* W1 = (const float*)d_in[4];
  const float* b1 = (const float*)d_in[5];
  const float* W2 = (const float*)d_in[6];
  const float* b2 = (const float*)d_in[7];
  float* out = (float*)d_out;

  const int N = in_sizes[0] / D;   // 100000
  const int E = in_sizes[1] / 2;   // 3200000

  char* wsb = (char*)d_ws;
  auto alloc = [&](size_t bytes) {
    char* p = wsb;
    wsb += ((bytes + 255) & ~(size_t)255);
    return p;
  };
  int*    rowptr = (int*)alloc((N + 1) * 4);
  int*    cursor = (int*)alloc(N * 4);      // also deg histogram
  int*    part   = (int*)alloc(256 * 4);
  float*  dinv   = (float*)alloc(N * 4);
  int*    csr    = (int*)alloc((size_t)E * 4);
  __half* th     = (__half*)alloc((size_t)N * D * 2);   // fp16 src-scaled features
  __half* g1h    = (__half*)alloc((size_t)N * D * 2);   // h1 fp16
  __half* g2h    = (__half*)alloc((size_t)N * D * 2);   // h2 fp16

  dim3 b256(256);
  int gN   = (N + 255) / 256;
  int gE   = (E + 255) / 256;
  int gGem = (N + 127) / 128;
  int gAgg = (N + 15) / 16;
  int nparts = (N + 2047) / 2048;

  // ---- CSR build (once; reused by all 3 layers) ----
  int* deg = cursor;
  k_zero_int<<<gN, b256, 0, stream>>>(deg, N);
  k_deg_count<<<gE, b256, 0, stream>>>(ei, deg, E);
  k_scan_part<<<nparts, b256, 0, stream>>>(deg, part, N);
  k_scan_offsets<<<1, b256, 0, stream>>>(part, nparts, rowptr, N);
  k_scan_final<<<nparts, b256, 0, stream>>>(deg, part, rowptr, N);
  k_dinv_cursor<<<gN, b256, 0, stream>>>(rowptr, dinv, cursor, N);
  const int NB = 4;
  int bsz = (N + NB - 1) / NB;
  for (int b = 0; b < NB; b++) {
    int lo = b * bsz;
    int hi = lo + bsz;
    if (hi > N) hi = N;
    k_csr_fill_b<<<gE, b256, 0, stream>>>(ei, cursor, csr, E, lo, hi);
  }

  // ---- layer 0: g1 = relu(Agg(x@W0) + b0)  [fp16] ----
  k_gemm_mfma<0><<<gGem, b256, 0, stream>>>(x, W0, dinv, th, N);
  k_aggregate<0><<<gAgg, b256, 0, stream>>>(rowptr, csr, dinv, th, b0, nullptr, g1h, nullptr, N);

  // ---- layer 1: h2 = relu(Agg(g1@W1) + b1 + g1)  [fp16] ----
  k_gemm_mfma<1><<<gGem, b256, 0, stream>>>(g1h, W1, dinv, th, N);
  k_aggregate<1><<<gAgg, b256, 0, stream>>>(rowptr, csr, dinv, th, b1, g1h, g2h, nullptr, N);

  // ---- layer 2: out = Agg(h2@W2) + b2  [f32 -> d_out] ----
  k_gemm_mfma<1><<<gGem, b256, 0, stream>>>(g2h, W2, dinv, th, N);
  k_aggregate<2><<<gAgg, b256, 0, stream>>>(rowptr, csr, dinv, th, b2, nullptr, nullptr, out, N);
}

// Round 10
// 746.349 us; speedup vs baseline: 4.0218x; 1.0909x over previous
//
#include <hip/hip_runtime.h>
#include <hip/hip_fp16.h>

#define D 128
typedef unsigned long long ull;
typedef _Float16 half8 __attribute__((ext_vector_type(8)));
typedef _Float16 half4v __attribute__((ext_vector_type(4)));
typedef float f32x4 __attribute__((ext_vector_type(4)));

// k-permutation: quartet k4 -> LDS pos so each MFMA fragment is one ds_read_b128
#define KPOS(k4) (((k4) & ~31) + ((((k4) & 15) >> 2) << 3) + ((((k4) >> 4) & 1) << 2))

__global__ void k_zero_int(int* p, int n) {
  int i = blockIdx.x * blockDim.x + threadIdx.x;
  if (i < n) p[i] = 0;
}

// ---- XCD-privatized degree histogram: copy = blockIdx&7 (round-robin -> same XCD) ----
__global__ void k_deg_count8(const int* __restrict__ ei, int* __restrict__ deg8,
                             int E, int N) {
  int e = blockIdx.x * blockDim.x + threadIdx.x;
  if (e >= E) return;
  int d = __builtin_nontemporal_load(&ei[E + e]);
  atomicAdd(&deg8[(blockIdx.x & 7) * N + d], 1);
}

__global__ void k_deg_reduce(const int* __restrict__ deg8, int* __restrict__ deg, int N) {
  int i = blockIdx.x * blockDim.x + threadIdx.x;
  if (i >= N) return;
  int s = 0;
#pragma unroll
  for (int c = 0; c < 8; c++) s += deg8[c * N + i];
  deg[i] = s;
}

// ---------------- prefix sum (CHUNK = 2048 = 256 threads x 8) ----------------
__global__ void k_scan_part(const int* __restrict__ deg, int* __restrict__ part, int n) {
  __shared__ int sd[256];
  int base = blockIdx.x * 2048 + threadIdx.x * 8;
  int s = 0;
#pragma unroll
  for (int k = 0; k < 8; k++) {
    int idx = base + k;
    if (idx < n) s += deg[idx];
  }
  sd[threadIdx.x] = s;
  __syncthreads();
  for (int off = 128; off > 0; off >>= 1) {
    if (threadIdx.x < off) sd[threadIdx.x] += sd[threadIdx.x + off];
    __syncthreads();
  }
  if (threadIdx.x == 0) part[blockIdx.x] = sd[0];
}

__global__ void k_scan_offsets(int* __restrict__ part, int nparts,
                               int* __restrict__ rowptr, int n) {
  __shared__ int sd[256];
  int v = (threadIdx.x < nparts) ? part[threadIdx.x] : 0;
  sd[threadIdx.x] = v;
  __syncthreads();
  for (int off = 1; off < 256; off <<= 1) {
    int t = (threadIdx.x >= off) ? sd[threadIdx.x - off] : 0;
    __syncthreads();
    sd[threadIdx.x] += t;
    __syncthreads();
  }
  if (threadIdx.x < nparts) part[threadIdx.x] = sd[threadIdx.x] - v;  // exclusive
  if (threadIdx.x == 0) rowptr[n] = sd[255];                          // total = E
}

__global__ void k_scan_final(const int* __restrict__ deg, const int* __restrict__ part,
                             int* __restrict__ rowptr, int n) {
  __shared__ int sd[256];
  int base = blockIdx.x * 2048 + threadIdx.x * 8;
  int loc[8];
  int s = 0;
#pragma unroll
  for (int k = 0; k < 8; k++) {
    int idx = base + k;
    loc[k] = (idx < n) ? deg[idx] : 0;
    s += loc[k];
  }
  sd[threadIdx.x] = s;
  __syncthreads();
  for (int off = 1; off < 256; off <<= 1) {
    int t = (threadIdx.x >= off) ? sd[threadIdx.x - off] : 0;
    __syncthreads();
    sd[threadIdx.x] += t;
    __syncthreads();
  }
  int run = part[blockIdx.x] + sd[threadIdx.x] - s;  // exclusive offset
#pragma unroll
  for (int k = 0; k < 8; k++) {
    int idx = base + k;
    if (idx < n) {
      rowptr[idx] = run;
      run += loc[k];
    }
  }
}

// dinv = rsqrt(in_deg + 1 self-loop); also init cursor = rowptr
__global__ void k_dinv_cursor(const int* __restrict__ rowptr, float* __restrict__ dinv,
                              int* __restrict__ cursor, int n) {
  int i = blockIdx.x * blockDim.x + threadIdx.x;
  if (i < n) {
    int r0 = rowptr[i], r1 = rowptr[i + 1];
    dinv[i] = rsqrtf((float)(r1 - r0) + 1.0f);
    cursor[i] = r0;
  }
}

// ---- single-pass bucketed fill: bucket = blockIdx&7 (XCD-local cursor atomics),
//      slice = blockIdx>>3 covers a contiguous edge chunk. ----
__global__ void k_csr_fill_x(const int* __restrict__ ei, int* __restrict__ cursor,
                             int* __restrict__ csr, int E, int bsz) {
  const int bucket = blockIdx.x & 7;
  const int slice = blockIdx.x >> 3;
  const int nsl = gridDim.x >> 3;
  const int lo = bucket * bsz;
  const int chunk = (E + nsl - 1) / nsl;
  const int start = slice * chunk;
  int endE = start + chunk;
  if (endE > E) endE = E;
  for (int e = start + threadIdx.x; e < endE; e += 256) {
    int d = __builtin_nontemporal_load(&ei[E + e]);
    if ((unsigned)(d - lo) < (unsigned)bsz) {
      int s = __builtin_nontemporal_load(&ei[e]);
      int pos = atomicAdd(&cursor[d], 1);
      csr[pos] = s;
    }
  }
}

// ---------------- MFMA GEMM: Th[n,128](fp16) = (A[n,128] @ W[128,128]) * dinv[row] ----
// mfma_f32_16x16x32_f16, 128x128 tile, 4 waves. A input f32 (HALF_IN=0) or fp16 (HALF_IN=1).
template <int HALF_IN>
__launch_bounds__(256, 2)
__global__ void k_gemm_mfma(const void* __restrict__ Av, const float* __restrict__ W,
                            const float* __restrict__ dinv, __half* __restrict__ Th, int n) {
  __shared__ _Float16 Al[128 * 136];
  __shared__ _Float16 Bl[128 * 136];
  const int tid = threadIdx.x;
  const int row0 = blockIdx.x * 128;

  if (HALF_IN) {
    const _Float16* A = (const _Float16*)Av;
    for (int i = tid; i < 2048; i += 256) {   // 128 rows x 16 chunks of 8 halves
      int r = i >> 4;
      int k8 = (i & 15) << 3;
      half8 v = {0, 0, 0, 0, 0, 0, 0, 0};
      if (row0 + r < n) v = *(const half8*)&A[(size_t)(row0 + r) * D + k8];
      *(half4v*)&Al[r * 136 + KPOS(k8)]     = (half4v){v[0], v[1], v[2], v[3]};
      *(half4v*)&Al[r * 136 + KPOS(k8 + 4)] = (half4v){v[4], v[5], v[6], v[7]};
    }
  } else {
    const float* A = (const float*)Av;
    for (int i = tid; i < 4096; i += 256) {
      int r = i >> 5;
      int k4 = (i & 31) << 2;
      float4 v = make_float4(0.f, 0.f, 0.f, 0.f);
      if (row0 + r < n) v = ((const float4*)A)[(size_t)(row0 + r) * 32 + (i & 31)];
      *(half4v*)&Al[r * 136 + KPOS(k4)] =
          (half4v){(_Float16)v.x, (_Float16)v.y, (_Float16)v.z, (_Float16)v.w};
    }
  }
  // stage W transposed: consecutive tid = consecutive c (coalesced)
  for (int i = tid; i < 4096; i += 256) {
    int c = i & 127;
    int k4 = (i >> 7) << 2;
    float w0 = W[(k4 + 0) * D + c];
    float w1 = W[(k4 + 1) * D + c];
    float w2 = W[(k4 + 2) * D + c];
    float w3 = W[(k4 + 3) * D + c];
    *(half4v*)&Bl[c * 136 + KPOS(k4)] =
        (half4v){(_Float16)w0, (_Float16)w1, (_Float16)w2, (_Float16)w3};
  }
  __syncthreads();

  const int w = tid >> 6;
  const int lane = tid & 63;
  const int g = lane >> 4;
  const int q = lane & 15;

  f32x4 acc[2][8];
#pragma unroll
  for (int mt = 0; mt < 2; mt++)
#pragma unroll
    for (int nt = 0; nt < 8; nt++) acc[mt][nt] = (f32x4){0.f, 0.f, 0.f, 0.f};

#pragma unroll
  for (int kt = 0; kt < 4; kt++) {
    half8 a[2], b[8];
#pragma unroll
    for (int mt = 0; mt < 2; mt++)
      a[mt] = *(const half8*)&Al[(w * 32 + mt * 16 + q) * 136 + kt * 32 + g * 8];
#pragma unroll
    for (int nt = 0; nt < 8; nt++)
      b[nt] = *(const half8*)&Bl[(nt * 16 + q) * 136 + kt * 32 + g * 8];
#pragma unroll
    for (int mt = 0; mt < 2; mt++)
#pragma unroll
      for (int nt = 0; nt < 8; nt++)
        acc[mt][nt] = __builtin_amdgcn_mfma_f32_16x16x32_f16(a[mt], b[nt], acc[mt][nt], 0, 0, 0);
  }

  // epilogue: D[row=4g+r][col=q] per tile; scale by dinv[row], store fp16
#pragma unroll
  for (int mt = 0; mt < 2; mt++) {
    int baseRow = row0 + w * 32 + mt * 16 + g * 4;
    float dv[4];
#pragma unroll
    for (int r = 0; r < 4; r++) dv[r] = (baseRow + r < n) ? dinv[baseRow + r] : 0.f;
#pragma unroll
    for (int nt = 0; nt < 8; nt++) {
      int col = nt * 16 + q;
#pragma unroll
      for (int r = 0; r < 4; r++) {
        int gr = baseRow + r;
        if (gr < n) Th[(size_t)gr * D + col] = (__half)(acc[mt][nt][r] * dv[r]);
      }
    }
  }
}

// ---------------- pull-style aggregation (fp16 gathers, unroll 8) ----------------
// th pre-scaled by dinv[row]:  acc = dinv[d]*(th[d] + sum th[src]) + b  [+res] [relu]
// 16 lanes per node (lane owns 8 cols = 16B fp16), 4 nodes per wave.
// MODE 0: relu -> fp16 out; MODE 1: relu(+res fp16) -> fp16 out; MODE 2: raw -> f32 out
template <int MODE>
__launch_bounds__(256)
__global__ void k_aggregate(const int* __restrict__ rowptr, const int* __restrict__ csr,
                            const float* __restrict__ dinv, const __half* __restrict__ th,
                            const float* __restrict__ b, const __half* __restrict__ resh,
                            __half* __restrict__ outh, float* __restrict__ outf, int n) {
  int node = blockIdx.x * 16 + (threadIdx.x >> 4);
  if (node >= n) return;
  const int l16 = threadIdx.x & 15;

  int beg = rowptr[node];
  int end = rowptr[node + 1];
  float dd = dinv[node];

  const float4* t4 = (const float4*)th;   // float4 = 8 halves = 16B

  float a0, a1, a2, a3, a4, a5, a6, a7;
  {
    float4 raw = t4[(size_t)node * 16 + l16];   // self term
    const __half2* hp = (const __half2*)&raw;
    float2 f0 = __half22float2(hp[0]);
    float2 f1 = __half22float2(hp[1]);
    float2 f2 = __half22float2(hp[2]);
    float2 f3 = __half22float2(hp[3]);
    a0 = f0.x; a1 = f0.y; a2 = f1.x; a3 = f1.y;
    a4 = f2.x; a5 = f2.y; a6 = f3.x; a7 = f3.y;
  }

#define ACC_ROW(raw)                                  \
  {                                                   \
    const __half2* hp = (const __half2*)&(raw);       \
    float2 f0 = __half22float2(hp[0]);                \
    float2 f1 = __half22float2(hp[1]);                \
    float2 f2 = __half22float2(hp[2]);                \
    float2 f3 = __half22float2(hp[3]);                \
    a0 += f0.x; a1 += f0.y; a2 += f1.x; a3 += f1.y;   \
    a4 += f2.x; a5 += f2.y; a6 += f3.x; a7 += f3.y;   \
  }

  int j = beg;
  for (; j + 8 <= end; j += 8) {
    float4 r0, r1, r2, r3, r4, r5, r6, r7;
    {
      int s0 = __builtin_nontemporal_load(&csr[j + 0]);
      int s1 = __builtin_nontemporal_load(&csr[j + 1]);
      int s2 = __builtin_nontemporal_load(&csr[j + 2]);
      int s3 = __builtin_nontemporal_load(&csr[j + 3]);
      int s4 = __builtin_nontemporal_load(&csr[j + 4]);
      int s5 = __builtin_nontemporal_load(&csr[j + 5]);
      int s6 = __builtin_nontemporal_load(&csr[j + 6]);
      int s7 = __builtin_nontemporal_load(&csr[j + 7]);
      r0 = t4[(size_t)(unsigned)s0 * 16 + l16];
      r1 = t4[(size_t)(unsigned)s1 * 16 + l16];
      r2 = t4[(size_t)(unsigned)s2 * 16 + l16];
      r3 = t4[(size_t)(unsigned)s3 * 16 + l16];
      r4 = t4[(size_t)(unsigned)s4 * 16 + l16];
      r5 = t4[(size_t)(unsigned)s5 * 16 + l16];
      r6 = t4[(size_t)(unsigned)s6 * 16 + l16];
      r7 = t4[(size_t)(unsigned)s7 * 16 + l16];
    }
    ACC_ROW(r0) ACC_ROW(r1) ACC_ROW(r2) ACC_ROW(r3)
    ACC_ROW(r4) ACC_ROW(r5) ACC_ROW(r6) ACC_ROW(r7)
  }
  for (; j + 4 <= end; j += 4) {
    int s0 = __builtin_nontemporal_load(&csr[j + 0]);
    int s1 = __builtin_nontemporal_load(&csr[j + 1]);
    int s2 = __builtin_nontemporal_load(&csr[j + 2]);
    int s3 = __builtin_nontemporal_load(&csr[j + 3]);
    float4 r0 = t4[(size_t)(unsigned)s0 * 16 + l16];
    float4 r1 = t4[(size_t)(unsigned)s1 * 16 + l16];
    float4 r2 = t4[(size_t)(unsigned)s2 * 16 + l16];
    float4 r3 = t4[(size_t)(unsigned)s3 * 16 + l16];
    ACC_ROW(r0) ACC_ROW(r1) ACC_ROW(r2) ACC_ROW(r3)
  }
  for (; j < end; ++j) {
    int s = __builtin_nontemporal_load(&csr[j]);
    float4 r = t4[(size_t)(unsigned)s * 16 + l16];
    ACC_ROW(r)
  }
#undef ACC_ROW

  const float4* b4 = (const float4*)b;
  float4 bb0 = b4[l16 * 2];
  float4 bb1 = b4[l16 * 2 + 1];
  float o0 = fmaf(a0, dd, bb0.x), o1 = fmaf(a1, dd, bb0.y);
  float o2 = fmaf(a2, dd, bb0.z), o3 = fmaf(a3, dd, bb0.w);
  float o4 = fmaf(a4, dd, bb1.x), o5 = fmaf(a5, dd, bb1.y);
  float o6 = fmaf(a6, dd, bb1.z), o7 = fmaf(a7, dd, bb1.w);

  if (MODE == 1) {
    float4 raw = ((const float4*)resh)[(size_t)node * 16 + l16];
    const __half2* hp = (const __half2*)&raw;
    float2 f0 = __half22float2(hp[0]);
    float2 f1 = __half22float2(hp[1]);
    float2 f2 = __half22float2(hp[2]);
    float2 f3 = __half22float2(hp[3]);
    o0 += f0.x; o1 += f0.y; o2 += f1.x; o3 += f1.y;
    o4 += f2.x; o5 += f2.y; o6 += f3.x; o7 += f3.y;
  }
  if (MODE == 0 || MODE == 1) {
    o0 = fmaxf(o0, 0.f); o1 = fmaxf(o1, 0.f); o2 = fmaxf(o2, 0.f); o3 = fmaxf(o3, 0.f);
    o4 = fmaxf(o4, 0.f); o5 = fmaxf(o5, 0.f); o6 = fmaxf(o6, 0.f); o7 = fmaxf(o7, 0.f);
    union { __half2 h[4]; float4 f; } pk;
    pk.h[0] = __floats2half2_rn(o0, o1);
    pk.h[1] = __floats2half2_rn(o2, o3);
    pk.h[2] = __floats2half2_rn(o4, o5);
    pk.h[3] = __floats2half2_rn(o6, o7);
    ((float4*)outh)[(size_t)node * 16 + l16] = pk.f;
  } else {
    ((float4*)outf)[(size_t)node * 32 + l16 * 2] = make_float4(o0, o1, o2, o3);
    ((float4*)outf)[(size_t)node * 32 + l16 * 2 + 1] = make_float4(o4, o5, o6, o7);
  }
}

extern "C" void kernel_launch(void* const* d_in, const int* in_sizes, int n_in,
                              void* d_out, int out_size, void* d_ws, size_t ws_size,
                              hipStream_t stream) {
  const float* x  = (const float*)d_in[0];
  const int*   ei = (const int*)d_in[1];
  const float* W0 = (const float*)d_in[2];
  const float* b0 = (const float*)d_in[3];
  const float* W1 = (const float*)d_in[4];
  const float* b1 = (const float*)d_in[5];
  const float* W2 = (const float*)d_in[6];
  const float* b2 = (const float*)d_in[7];
  float* out = (float*)d_out;

  const int N = in_sizes[0] / D;   // 100000
  const int E = in_sizes[1] / 2;   // 3200000

  char* wsb = (char*)d_ws;
  auto alloc = [&](size_t bytes) {
    char* p = wsb;
    wsb += ((bytes + 255) & ~(size_t)255);
    return p;
  };
  int*    rowptr = (int*)alloc((N + 1) * 4);
  int*    cursor = (int*)alloc(N * 4);      // also deg (reduced) pre-scan
  int*    part   = (int*)alloc(256 * 4);
  float*  dinv   = (float*)alloc(N * 4);
  int*    deg8   = (int*)alloc((size_t)8 * N * 4);
  int*    csr    = (int*)alloc((size_t)E * 4);
  __half* th     = (__half*)alloc((size_t)N * D * 2);   // fp16 src-scaled features
  __half* g1h    = (__half*)alloc((size_t)N * D * 2);   // h1 fp16
  __half* g2h    = (__half*)alloc((size_t)N * D * 2);   // h2 fp16

  dim3 b256(256);
  int gN   = (N + 255) / 256;
  int gN8  = (8 * N + 255) / 256;
  int gE   = (E + 255) / 256;
  int gGem = (N + 127) / 128;
  int gAgg = (N + 15) / 16;
  int nparts = (N + 2047) / 2048;

  // ---- CSR build (once; reused by all 3 layers) ----
  int* deg = cursor;
  k_zero_int<<<gN8, b256, 0, stream>>>(deg8, 8 * N);
  k_deg_count8<<<gE, b256, 0, stream>>>(ei, deg8, E, N);
  k_deg_reduce<<<gN, b256, 0, stream>>>(deg8, deg, N);
  k_scan_part<<<nparts, b256, 0, stream>>>(deg, part, N);
  k_scan_offsets<<<1, b256, 0, stream>>>(part, nparts, rowptr, N);
  k_scan_final<<<nparts, b256, 0, stream>>>(deg, part, rowptr, N);
  k_dinv_cursor<<<gN, b256, 0, stream>>>(rowptr, dinv, cursor, N);
  int bsz = (N + 7) / 8;
  k_csr_fill_x<<<8 * 256, b256, 0, stream>>>(ei, cursor, csr, E, bsz);

  // ---- layer 0: g1 = relu(Agg(x@W0) + b0)  [fp16] ----
  k_gemm_mfma<0><<<gGem, b256, 0, stream>>>(x, W0, dinv, th, N);
  k_aggregate<0><<<gAgg, b256, 0, stream>>>(rowptr, csr, dinv, th, b0, nullptr, g1h, nullptr, N);

  // ---- layer 1: h2 = relu(Agg(g1@W1) + b1 + g1)  [fp16] ----
  k_gemm_mfma<1><<<gGem, b256, 0, stream>>>(g1h, W1, dinv, th, N);
  k_aggregate<1><<<gAgg, b256, 0, stream>>>(rowptr, csr, dinv, th, b1, g1h, g2h, nullptr, N);

  // ---- layer 2: out = Agg(h2@W2) + b2  [f32 -> d_out] ----
  k_gemm_mfma<1><<<gGem, b256, 0, stream>>>(g2h, W2, dinv, th, N);
  k_aggregate<2><<<gAgg, b256, 0, stream>>>(rowptr, csr, dinv, th, b2, nullptr, nullptr, out, N);
}